// Round 1
// baseline (3717.144 us; speedup 1.0000x reference)
//
#include <hip/hip_runtime.h>
#include <cstdint>
#include <cstddef>

// ---------------------------------------------------------------------------
// Problem constants (B=1)
//   D=2048, NH=16, DH=128, DC=512, DCQ=1024, L=2048
// ---------------------------------------------------------------------------

#define TILE 64
#define KSTEP 16

// C(M,N) = A(M,K) @ B(K,N), all row-major fp32. M,N multiples of 64, K of 16.
__global__ __launch_bounds__(256) void gemm_f32(const float* __restrict__ A,
                                                const float* __restrict__ B,
                                                float* __restrict__ C,
                                                int M, int N, int K) {
  __shared__ float As[KSTEP][TILE];   // k-major: As[k][m]
  __shared__ float Bs[KSTEP][TILE];   // Bs[k][n]
  const int bm = blockIdx.y * TILE;
  const int bn = blockIdx.x * TILE;
  const int tid = threadIdx.x;
  const int tr = (tid >> 4) << 2;     // 0..60
  const int tc = (tid & 15) << 2;     // 0..60
  const int ar = tid >> 2;            // A tile row 0..63
  const int ak = (tid & 3) << 2;      // A tile k 0..12
  const int bk = tid >> 4;            // B tile k 0..15
  const int bc = (tid & 15) << 2;     // B tile col 0..60
  float acc[4][4] = {};
  for (int k0 = 0; k0 < K; k0 += KSTEP) {
    float4 a = *(const float4*)&A[(size_t)(bm + ar) * K + k0 + ak];
    float4 b = *(const float4*)&B[(size_t)(k0 + bk) * N + bn + bc];
    As[ak + 0][ar] = a.x;
    As[ak + 1][ar] = a.y;
    As[ak + 2][ar] = a.z;
    As[ak + 3][ar] = a.w;
    *(float4*)&Bs[bk][bc] = b;
    __syncthreads();
#pragma unroll
    for (int kk = 0; kk < KSTEP; ++kk) {
      float4 av = *(float4*)&As[kk][tr];
      float4 bv = *(float4*)&Bs[kk][tc];
      float aa[4] = {av.x, av.y, av.z, av.w};
      float bb[4] = {bv.x, bv.y, bv.z, bv.w};
#pragma unroll
      for (int i = 0; i < 4; ++i)
#pragma unroll
        for (int j = 0; j < 4; ++j)
          acc[i][j] += aa[i] * bb[j];
    }
    __syncthreads();
  }
#pragma unroll
  for (int i = 0; i < 4; ++i) {
    float4 o = {acc[i][0], acc[i][1], acc[i][2], acc[i][3]};
    *(float4*)&C[(size_t)(bm + tr + i) * N + bn + tc] = o;
  }
}

// cos/sin tables: (L, 128).  inv_freq[j] = 10000^(-j/64), j = d & 63.
__global__ void rope_table_kernel(float* __restrict__ cosT,
                                  float* __restrict__ sinT) {
  const int l = blockIdx.x;
  const int d = threadIdx.x;  // 0..127
  const int j = d & 63;
  const float inv = powf(10000.0f, -(float)j * (1.0f / 64.0f));
  const float ang = (float)l * inv;
  cosT[l * 128 + d] = cosf(ang);
  sinT[l * 128 + d] = sinf(ang);
}

// In-place RoPE on a (2048, W) row-major tensor; heads of 128 along W.
__global__ __launch_bounds__(256) void rope_kernel(float* __restrict__ T,
                                                   const float* __restrict__ cosT,
                                                   const float* __restrict__ sinT,
                                                   int W) {
  __shared__ float row[4096];
  const int l = blockIdx.x;
  const int tid = threadIdx.x;
  float* rp = T + (size_t)l * W;
  for (int e = tid << 2; e < W; e += 1024)
    *(float4*)&row[e] = *(const float4*)&rp[e];
  __syncthreads();
  for (int e = tid; e < W; e += 256) {
    const int d = e & 127;
    const float c = cosT[l * 128 + d];
    const float s = sinT[l * 128 + d];
    const float t = row[e];
    const float rot = (d < 64) ? -row[e + 64] : row[e - 64];
    rp[e] = t * c + rot * s;
  }
}

// lam(l,h) = sigmoid( x[l,:] . W_lam[:,h] + b_lam[h] ), one block per row l.
__global__ __launch_bounds__(256) void lam_kernel(const float* __restrict__ x,
                                                  const float* __restrict__ W_lam,
                                                  const float* __restrict__ b_lam,
                                                  float* __restrict__ lam) {
  __shared__ float xr[2048];
  __shared__ float part[16][17];
  const int l = blockIdx.x;
  const int tid = threadIdx.x;
#pragma unroll
  for (int i = 0; i < 2; ++i) {
    const int e4 = tid + 256 * i;  // 0..511
    *(float4*)&xr[e4 << 2] = *(const float4*)&x[(size_t)l * 2048 + (e4 << 2)];
  }
  __syncthreads();
  const int h = tid >> 4;
  const int seg = tid & 15;
  float s = 0.f;
  for (int k = seg * 128; k < seg * 128 + 128; ++k)
    s += xr[k] * W_lam[k * 16 + h];
  part[h][seg] = s;
  __syncthreads();
  if (tid < 16) {
    float t = b_lam[tid];
#pragma unroll
    for (int i = 0; i < 16; ++i) t += part[tid][i];
    lam[l * 16 + tid] = 1.0f / (1.0f + expf(-t));
  }
}

// Causal flash attention.
//  Qr: (2048, 4096) roped q (32 heads), Kr: (2048, 2048) roped k (16 heads),
//  Vr: (2048, 2048) v (16 heads).  O: (32, 2048, 128).
//  Q-head h32 uses KV head h32>>1.
#define AQ 64
#define AK 32
__global__ __launch_bounds__(256) void attn_kernel(const float* __restrict__ Qr,
                                                   const float* __restrict__ Kr,
                                                   const float* __restrict__ Vr,
                                                   float* __restrict__ O) {
  __shared__ float Qs[AQ][132];      // padded
  __shared__ float KVs[AK][132];     // K then V, reused
  __shared__ float S[AQ][AK + 1];    // scores then P
  __shared__ float alphas[AQ];
  __shared__ float lfin[AQ];
  const int h32 = blockIdx.y;
  const int q0 = blockIdx.x * AQ;
  const int qoff = h32 * 128;
  const int kvoff = (h32 >> 1) * 128;
  const int tid = threadIdx.x;
  const float scale = 0.08838834764831845f;  // 1/sqrt(128)

#pragma unroll
  for (int i = 0; i < 8; ++i) {
    const int f4 = tid + 256 * i;        // 0..2047
    const int r = f4 >> 5;               // 32 float4 per row
    const int c4 = (f4 & 31) << 2;
    *(float4*)&Qs[r][c4] = *(const float4*)&Qr[(size_t)(q0 + r) * 4096 + qoff + c4];
  }

  const int rg = tid >> 4;  // 0..15: rows rg*4 .. rg*4+3
  const int cg = tid & 15;  // 0..15: score cols cg*2..+1; PV dims cg*8..+7
  float o[4][8];
#pragma unroll
  for (int i = 0; i < 4; ++i)
#pragma unroll
    for (int d = 0; d < 8; ++d) o[i][d] = 0.f;
  float m_r = -1e30f, l_r = 0.f;  // owned by thread tid (<64) for row tid

  const int ktmax = (q0 + AQ - 1) / AK;
  for (int kt = 0; kt <= ktmax; ++kt) {
    const int k0 = kt * AK;
    __syncthreads();  // Q load done (iter0) / prev PV reads of KVs done
    // ---- load K tile (32x128) ----
#pragma unroll
    for (int i = 0; i < 4; ++i) {
      const int f4 = tid + 256 * i;      // 0..1023
      const int r = f4 >> 5;
      const int c4 = (f4 & 31) << 2;
      *(float4*)&KVs[r][c4] = *(const float4*)&Kr[(size_t)(k0 + r) * 2048 + kvoff + c4];
    }
    __syncthreads();
    // ---- scores S = Q K^T ----
    float acc[4][2] = {};
#pragma unroll
    for (int d4 = 0; d4 < 32; ++d4) {
      const float4 kv0 = *(float4*)&KVs[cg * 2 + 0][d4 << 2];
      const float4 kv1 = *(float4*)&KVs[cg * 2 + 1][d4 << 2];
#pragma unroll
      for (int i = 0; i < 4; ++i) {
        const float4 q4 = *(float4*)&Qs[rg * 4 + i][d4 << 2];
        acc[i][0] += q4.x * kv0.x + q4.y * kv0.y + q4.z * kv0.z + q4.w * kv0.w;
        acc[i][1] += q4.x * kv1.x + q4.y * kv1.y + q4.z * kv1.z + q4.w * kv1.w;
      }
    }
#pragma unroll
    for (int i = 0; i < 4; ++i) {
      S[rg * 4 + i][cg * 2 + 0] = acc[i][0];
      S[rg * 4 + i][cg * 2 + 1] = acc[i][1];
    }
    __syncthreads();
    // ---- load V tile (overwrites K; scores already consumed) ----
#pragma unroll
    for (int i = 0; i < 4; ++i) {
      const int f4 = tid + 256 * i;
      const int r = f4 >> 5;
      const int c4 = (f4 & 31) << 2;
      *(float4*)&KVs[r][c4] = *(const float4*)&Vr[(size_t)(k0 + r) * 2048 + kvoff + c4];
    }
    // ---- online softmax (one thread per q row) ----
    if (tid < AQ) {
      const int r = tid;
      const int q = q0 + r;
      float mx = -1e30f;
#pragma unroll
      for (int c = 0; c < AK; ++c) {
        const float s = (k0 + c <= q) ? S[r][c] * scale : -1e30f;
        mx = fmaxf(mx, s);
      }
      const float mnew = fmaxf(m_r, mx);
      const float alpha = expf(m_r - mnew);
      float lsum = 0.f;
#pragma unroll
      for (int c = 0; c < AK; ++c) {
        const float s = (k0 + c <= q) ? S[r][c] * scale : -1e30f;
        const float p = expf(s - mnew);
        S[r][c] = p;
        lsum += p;
      }
      m_r = mnew;
      l_r = l_r * alpha + lsum;
      alphas[r] = alpha;
      lfin[r] = l_r;
    }
    __syncthreads();
    // ---- O = alpha*O + P V ----
#pragma unroll
    for (int i = 0; i < 4; ++i) {
      const float a = alphas[rg * 4 + i];
#pragma unroll
      for (int d = 0; d < 8; ++d) o[i][d] *= a;
    }
#pragma unroll
    for (int k = 0; k < AK; ++k) {
      const float4 v0 = *(float4*)&KVs[k][cg * 8];
      const float4 v1 = *(float4*)&KVs[k][cg * 8 + 4];
#pragma unroll
      for (int i = 0; i < 4; ++i) {
        const float p = S[rg * 4 + i][k];
        o[i][0] += p * v0.x; o[i][1] += p * v0.y;
        o[i][2] += p * v0.z; o[i][3] += p * v0.w;
        o[i][4] += p * v1.x; o[i][5] += p * v1.y;
        o[i][6] += p * v1.z; o[i][7] += p * v1.w;
      }
    }
  }
  __syncthreads();
#pragma unroll
  for (int i = 0; i < 4; ++i) {
    const int r = rg * 4 + i;
    const float inv = 1.0f / lfin[r];
    float4 o0 = {o[i][0] * inv, o[i][1] * inv, o[i][2] * inv, o[i][3] * inv};
    float4 o1 = {o[i][4] * inv, o[i][5] * inv, o[i][6] * inv, o[i][7] * inv};
    float* dst = O + ((size_t)h32 * 2048 + q0 + r) * 128 + cg * 8;
    *(float4*)&dst[0] = o0;
    *(float4*)&dst[4] = o1;
  }
}

// y[l, h*128+d] = attn[2h, l, d] - lam[l,h] * attn[2h+1, l, d]
__global__ __launch_bounds__(256) void combine_kernel(const float* __restrict__ attn,
                                                      const float* __restrict__ lam,
                                                      float* __restrict__ y) {
  const int l = blockIdx.x;
  const int tid = threadIdx.x;
#pragma unroll
  for (int i = 0; i < 2; ++i) {
    const int e = tid + 256 * i;   // float4 index over 2048 floats
    const int h = e >> 5;          // 32 float4 per head
    const int c4 = (e & 31) << 2;
    const float lm = lam[l * 16 + h];
    const float4 a1 = *(const float4*)&attn[((size_t)(2 * h) * 2048 + l) * 128 + c4];
    const float4 a2 = *(const float4*)&attn[((size_t)(2 * h + 1) * 2048 + l) * 128 + c4];
    float4 r = {a1.x - lm * a2.x, a1.y - lm * a2.y,
                a1.z - lm * a2.z, a1.w - lm * a2.w};
    *(float4*)&y[(size_t)l * 2048 + h * 128 + c4] = r;
  }
}

extern "C" void kernel_launch(void* const* d_in, const int* in_sizes, int n_in,
                              void* d_out, int out_size, void* d_ws, size_t ws_size,
                              hipStream_t stream) {
  const float* x     = (const float*)d_in[0];
  const float* W_DKV = (const float*)d_in[1];
  const float* W_UK  = (const float*)d_in[2];
  const float* W_UV  = (const float*)d_in[3];
  const float* W_DQ  = (const float*)d_in[4];
  const float* W_UQ  = (const float*)d_in[5];
  const float* W_lam = (const float*)d_in[6];
  const float* b_lam = (const float*)d_in[7];
  const float* W_out = (const float*)d_in[8];
  float* out = (float*)d_out;

  char* ws = (char*)d_ws;
  float* c_kv  = (float*)(ws);                        //  4 MB (2048x512)
  float* c_q   = (float*)(ws + ((size_t)4  << 20));   //  8 MB (2048x1024)
  float* k_raw = (float*)(ws + ((size_t)12 << 20));   // 16 MB (2048x2048)
  float* v_raw = (float*)(ws + ((size_t)28 << 20));   // 16 MB (2048x2048)
  float* q_raw = (float*)(ws + ((size_t)44 << 20));   // 32 MB (2048x4096)
  float* attn  = (float*)(ws + ((size_t)76 << 20));   // 32 MB (32x2048x128)
  float* lam   = (float*)(ws + ((size_t)108 << 20));  // 128 KB (2048x16)
  float* cosT  = (float*)(ws + ((size_t)109 << 20));  //  1 MB (2048x128)
  float* sinT  = (float*)(ws + ((size_t)110 << 20));  //  1 MB
  float* y     = q_raw;  // q_raw is dead after attention

  // RoPE tables
  rope_table_kernel<<<2048, 128, 0, stream>>>(cosT, sinT);
  // Projections
  gemm_f32<<<dim3(512 / 64, 2048 / 64),  256, 0, stream>>>(x,    W_DKV, c_kv,  2048, 512,  2048);
  gemm_f32<<<dim3(1024 / 64, 2048 / 64), 256, 0, stream>>>(x,    W_DQ,  c_q,   2048, 1024, 2048);
  gemm_f32<<<dim3(2048 / 64, 2048 / 64), 256, 0, stream>>>(c_kv, W_UK,  k_raw, 2048, 2048, 512);
  gemm_f32<<<dim3(2048 / 64, 2048 / 64), 256, 0, stream>>>(c_kv, W_UV,  v_raw, 2048, 2048, 512);
  gemm_f32<<<dim3(4096 / 64, 2048 / 64), 256, 0, stream>>>(c_q,  W_UQ,  q_raw, 2048, 4096, 1024);
  // RoPE (in place)
  rope_kernel<<<2048, 256, 0, stream>>>(k_raw, cosT, sinT, 2048);
  rope_kernel<<<2048, 256, 0, stream>>>(q_raw, cosT, sinT, 4096);
  // Gate
  lam_kernel<<<2048, 256, 0, stream>>>(x, W_lam, b_lam, lam);
  // Attention: grid (q-tiles, 32 q-heads)
  attn_kernel<<<dim3(2048 / AQ, 32), 256, 0, stream>>>(q_raw, k_raw, v_raw, attn);
  // Differential combine into y
  combine_kernel<<<2048, 256, 0, stream>>>(attn, lam, y);
  // Output projection
  gemm_f32<<<dim3(2048 / 64, 2048 / 64), 256, 0, stream>>>(y, W_out, out, 2048, 2048, 2048);
}

// Round 2
// 1300.518 us; speedup vs baseline: 2.8582x; 2.8582x over previous
//
#include <hip/hip_runtime.h>
#include <cstdint>
#include <cstddef>

typedef __bf16 bf16x8 __attribute__((ext_vector_type(8)));
typedef __bf16 bf16x4 __attribute__((ext_vector_type(4)));
typedef float f32x4 __attribute__((ext_vector_type(4)));

// ---------------------------------------------------------------------------
// Problem constants (B=1): D=2048, NH=16, DH=128, DC=512, DCQ=1024, L=2048
// ---------------------------------------------------------------------------

#define TILE 64
#define KSTEP 16

// C(M,N) = A(M,K) @ B(K,N), row-major fp32 inputs; C fp32 or bf16.
template <bool BF16OUT>
__global__ __launch_bounds__(256) void gemm_t(const float* __restrict__ A,
                                              const float* __restrict__ B,
                                              void* __restrict__ Cv,
                                              int M, int N, int K) {
  __shared__ float As[KSTEP][TILE];
  __shared__ float Bs[KSTEP][TILE];
  const int bm = blockIdx.y * TILE;
  const int bn = blockIdx.x * TILE;
  const int tid = threadIdx.x;
  const int tr = (tid >> 4) << 2;
  const int tc = (tid & 15) << 2;
  const int ar = tid >> 2;
  const int ak = (tid & 3) << 2;
  const int bk = tid >> 4;
  const int bc = (tid & 15) << 2;
  float acc[4][4] = {};
  for (int k0 = 0; k0 < K; k0 += KSTEP) {
    float4 a = *(const float4*)&A[(size_t)(bm + ar) * K + k0 + ak];
    float4 b = *(const float4*)&B[(size_t)(k0 + bk) * N + bn + bc];
    As[ak + 0][ar] = a.x;
    As[ak + 1][ar] = a.y;
    As[ak + 2][ar] = a.z;
    As[ak + 3][ar] = a.w;
    *(float4*)&Bs[bk][bc] = b;
    __syncthreads();
#pragma unroll
    for (int kk = 0; kk < KSTEP; ++kk) {
      float4 av = *(float4*)&As[kk][tr];
      float4 bv = *(float4*)&Bs[kk][tc];
      float aa[4] = {av.x, av.y, av.z, av.w};
      float bb[4] = {bv.x, bv.y, bv.z, bv.w};
#pragma unroll
      for (int i = 0; i < 4; ++i)
#pragma unroll
        for (int j = 0; j < 4; ++j)
          acc[i][j] += aa[i] * bb[j];
    }
    __syncthreads();
  }
#pragma unroll
  for (int i = 0; i < 4; ++i) {
    if constexpr (BF16OUT) {
      __bf16* C = (__bf16*)Cv;
      bf16x4 o = {(__bf16)acc[i][0], (__bf16)acc[i][1],
                  (__bf16)acc[i][2], (__bf16)acc[i][3]};
      *(bf16x4*)&C[(size_t)(bm + tr + i) * N + bn + tc] = o;
    } else {
      float* C = (float*)Cv;
      float4 o = {acc[i][0], acc[i][1], acc[i][2], acc[i][3]};
      *(float4*)&C[(size_t)(bm + tr + i) * N + bn + tc] = o;
    }
  }
}

// cos/sin tables: (L, 128).  inv_freq[j] = 10000^(-j/64), j = d & 63.
__global__ void rope_table_kernel(float* __restrict__ cosT,
                                  float* __restrict__ sinT) {
  const int l = blockIdx.x;
  const int d = threadIdx.x;  // 0..127
  const int j = d & 63;
  const float inv = powf(10000.0f, -(float)j * (1.0f / 64.0f));
  const float ang = (float)l * inv;
  cosT[l * 128 + d] = cosf(ang);
  sinT[l * 128 + d] = sinf(ang);
}

// In-place RoPE on a (2048, W) row-major bf16 tensor; heads of 128 along W.
__global__ __launch_bounds__(256) void rope_bf16_kernel(__bf16* __restrict__ T,
                                                        const float* __restrict__ cosT,
                                                        const float* __restrict__ sinT,
                                                        int W) {
  __shared__ float row[4096];
  const int l = blockIdx.x;
  const int tid = threadIdx.x;
  __bf16* rp = T + (size_t)l * W;
  for (int e4 = tid; e4 * 4 < W; e4 += 256) {
    bf16x4 v = *(const bf16x4*)&rp[e4 * 4];
#pragma unroll
    for (int i = 0; i < 4; ++i) row[e4 * 4 + i] = (float)v[i];
  }
  __syncthreads();
  for (int e = tid; e < W; e += 256) {
    const int d = e & 127;
    const float c = cosT[l * 128 + d];
    const float s = sinT[l * 128 + d];
    const float t = row[e];
    const int base = e & ~127;
    const float rot = (d < 64) ? -row[base + d + 64] : row[base + d - 64];
    rp[e] = (__bf16)(t * c + rot * s);
  }
}

// (2048 l, 2048 dims) bf16  ->  (2048 dims, 2048 l) bf16
__global__ __launch_bounds__(256) void transpose_bf16_kernel(const __bf16* __restrict__ src,
                                                             __bf16* __restrict__ dst) {
  __shared__ __align__(16) __bf16 Ts[32][40];
  const int l0 = blockIdx.x * 32;
  const int d0 = blockIdx.y * 32;
  const int r = threadIdx.x >> 3;        // 0..31
  const int c = (threadIdx.x & 7) * 4;   // 0..28
  *(bf16x4*)&Ts[r][c] = *(const bf16x4*)&src[(size_t)(l0 + r) * 2048 + d0 + c];
  __syncthreads();
  bf16x4 o = {Ts[c + 0][r], Ts[c + 1][r], Ts[c + 2][r], Ts[c + 3][r]};
  *(bf16x4*)&dst[(size_t)(d0 + r) * 2048 + l0 + c] = o;
}

// lam(l,h) = sigmoid( x[l,:] . W_lam[:,h] + b_lam[h] ), one block per row l.
__global__ __launch_bounds__(256) void lam_kernel(const float* __restrict__ x,
                                                  const float* __restrict__ W_lam,
                                                  const float* __restrict__ b_lam,
                                                  float* __restrict__ lam) {
  __shared__ float xr[2048];
  __shared__ float part[16][17];
  const int l = blockIdx.x;
  const int tid = threadIdx.x;
#pragma unroll
  for (int i = 0; i < 2; ++i) {
    const int e4 = tid + 256 * i;
    *(float4*)&xr[e4 << 2] = *(const float4*)&x[(size_t)l * 2048 + (e4 << 2)];
  }
  __syncthreads();
  const int h = tid >> 4;
  const int seg = tid & 15;
  float s = 0.f;
  for (int k = seg * 128; k < seg * 128 + 128; ++k)
    s += xr[k] * W_lam[k * 16 + h];
  part[h][seg] = s;
  __syncthreads();
  if (tid < 16) {
    float t = b_lam[tid];
#pragma unroll
    for (int i = 0; i < 16; ++i) t += part[tid][i];
    lam[l * 16 + tid] = 1.0f / (1.0f + expf(-t));
  }
}

// ---------------------------------------------------------------------------
// MFMA flash attention.
//  Qb: (2048, 4096) roped bf16 (32 q-heads).  Kb: (2048, 2048) roped bf16.
//  Vt: (2048 dims, 2048 l) bf16 (per-head dim-major).  O: (32, 2048, 128) f32.
//  Q-head h32 uses KV head h32>>1.
//  Block: 256 thr (4 waves); wave w owns Q rows q0+w*16 .. +15; K-tile 32.
//  MFMA 16x16x32: A[m=lane&15][k=quad*8+j], B[k=quad*8+j][n=lane&15],
//                 C/D: col=lane&15, row=quad*4+reg.
// ---------------------------------------------------------------------------
#define ATQ 64
__global__ __launch_bounds__(256) void attn_mfma_kernel(const __bf16* __restrict__ Qb,
                                                        const __bf16* __restrict__ Kb,
                                                        const __bf16* __restrict__ Vt,
                                                        float* __restrict__ O) {
  __shared__ __align__(16) __bf16 Ks[32][136];   // (key, dim) padded
  __shared__ __align__(16) __bf16 Vs[128][40];   // (dim, key) padded
  __shared__ __align__(16) __bf16 Ps[4][16][40]; // per-wave P (qrow, key)
  const int h32 = blockIdx.y;
  const int q0 = blockIdx.x * ATQ;
  const int tid = threadIdx.x;
  const int w = tid >> 6;
  const int lane = tid & 63;
  const int quad = lane >> 4;
  const int l16 = lane & 15;
  const int qoff = h32 * 128;
  const int kvoff = (h32 >> 1) * 128;
  const float scale = 0.08838834764831845f;  // 1/sqrt(128)

  // Q fragments (held all loop): A[m=l16][k=quad*8+j] per 32-dim k-step
  bf16x8 aq[4];
  {
    const size_t qbase = (size_t)(q0 + w * 16 + l16) * 4096 + qoff + quad * 8;
#pragma unroll
    for (int ks = 0; ks < 4; ++ks)
      aq[ks] = *(const bf16x8*)&Qb[qbase + ks * 32];
  }

  f32x4 o[8];
#pragma unroll
  for (int i = 0; i < 8; ++i) o[i] = (f32x4){0.f, 0.f, 0.f, 0.f};
  float m[4], lsum[4];
#pragma unroll
  for (int r = 0; r < 4; ++r) { m[r] = -1e30f; lsum[r] = 0.f; }

  const int ktmax = (q0 + ATQ - 1) / 32;
  for (int kt = 0; kt <= ktmax; ++kt) {
    const int k0 = kt * 32;
    __syncthreads();  // prev iter's PV reads of Ks/Vs done
    // ---- stage K (32x128) and V^T (128x32) ----
#pragma unroll
    for (int i = 0; i < 2; ++i) {
      const int f = tid + 256 * i;             // 0..511
      const int kr = f >> 4, seg = f & 15;
      *(bf16x8*)&Ks[kr][seg * 8] =
          *(const bf16x8*)&Kb[(size_t)(k0 + kr) * 2048 + kvoff + seg * 8];
      const int dr = f >> 2, sg2 = f & 3;
      *(bf16x8*)&Vs[dr][sg2 * 8] =
          *(const bf16x8*)&Vt[(size_t)(kvoff + dr) * 2048 + k0 + sg2 * 8];
    }
    __syncthreads();
    // ---- S = Q K^T : two 16-col n-tiles, 4 k-steps each ----
    f32x4 s0a = (f32x4){0.f, 0.f, 0.f, 0.f};
    f32x4 s1a = (f32x4){0.f, 0.f, 0.f, 0.f};
#pragma unroll
    for (int ks = 0; ks < 4; ++ks) {
      bf16x8 bk0 = *(bf16x8*)&Ks[l16][ks * 32 + quad * 8];
      bf16x8 bk1 = *(bf16x8*)&Ks[16 + l16][ks * 32 + quad * 8];
      s0a = __builtin_amdgcn_mfma_f32_16x16x32_bf16(aq[ks], bk0, s0a, 0, 0, 0);
      s1a = __builtin_amdgcn_mfma_f32_16x16x32_bf16(aq[ks], bk1, s1a, 0, 0, 0);
    }
    // ---- online softmax (in registers; rows = quad*4+r) ----
#pragma unroll
    for (int r = 0; r < 4; ++r) {
      const int q = q0 + w * 16 + quad * 4 + r;
      float v0 = (k0 + l16 <= q) ? s0a[r] * scale : -1e30f;
      float v1 = (k0 + 16 + l16 <= q) ? s1a[r] * scale : -1e30f;
      float rm = fmaxf(v0, v1);
#pragma unroll
      for (int off = 1; off < 16; off <<= 1)
        rm = fmaxf(rm, __shfl_xor(rm, off, 64));
      const float mn = fmaxf(m[r], rm);
      const float alpha = __expf(m[r] - mn);
      const float p0 = __expf(v0 - mn);
      const float p1 = __expf(v1 - mn);
      float rs = p0 + p1;
#pragma unroll
      for (int off = 1; off < 16; off <<= 1)
        rs += __shfl_xor(rs, off, 64);
      m[r] = mn;
      lsum[r] = lsum[r] * alpha + rs;
#pragma unroll
      for (int nt2 = 0; nt2 < 8; ++nt2) o[nt2][r] *= alpha;
      Ps[w][quad * 4 + r][l16] = (__bf16)p0;
      Ps[w][quad * 4 + r][16 + l16] = (__bf16)p1;
    }
    __syncthreads();  // make P visible (also keeps waves together)
    // ---- O += P V : P A-frag from LDS, V^T B-frags ----
    bf16x8 pa = *(bf16x8*)&Ps[w][l16][quad * 8];
#pragma unroll
    for (int nt2 = 0; nt2 < 8; ++nt2) {
      bf16x8 bv = *(bf16x8*)&Vs[nt2 * 16 + l16][quad * 8];
      o[nt2] = __builtin_amdgcn_mfma_f32_16x16x32_bf16(pa, bv, o[nt2], 0, 0, 0);
    }
  }
  // ---- epilogue ----
#pragma unroll
  for (int r = 0; r < 4; ++r) {
    const float inv = 1.0f / lsum[r];
    const int q = q0 + w * 16 + quad * 4 + r;
    float* dst = O + ((size_t)h32 * 2048 + q) * 128;
#pragma unroll
    for (int nt2 = 0; nt2 < 8; ++nt2)
      dst[nt2 * 16 + l16] = o[nt2][r] * inv;
  }
}

// y[l, h*128+d] = attn[2h, l, d] - lam[l,h] * attn[2h+1, l, d]
__global__ __launch_bounds__(256) void combine_kernel(const float* __restrict__ attn,
                                                      const float* __restrict__ lam,
                                                      float* __restrict__ y) {
  const int l = blockIdx.x;
  const int tid = threadIdx.x;
#pragma unroll
  for (int i = 0; i < 2; ++i) {
    const int e = tid + 256 * i;
    const int h = e >> 5;
    const int c4 = (e & 31) << 2;
    const float lm = lam[l * 16 + h];
    const float4 a1 = *(const float4*)&attn[((size_t)(2 * h) * 2048 + l) * 128 + c4];
    const float4 a2 = *(const float4*)&attn[((size_t)(2 * h + 1) * 2048 + l) * 128 + c4];
    float4 r = {a1.x - lm * a2.x, a1.y - lm * a2.y,
                a1.z - lm * a2.z, a1.w - lm * a2.w};
    *(float4*)&y[(size_t)l * 2048 + h * 128 + c4] = r;
  }
}

extern "C" void kernel_launch(void* const* d_in, const int* in_sizes, int n_in,
                              void* d_out, int out_size, void* d_ws, size_t ws_size,
                              hipStream_t stream) {
  const float* x     = (const float*)d_in[0];
  const float* W_DKV = (const float*)d_in[1];
  const float* W_UK  = (const float*)d_in[2];
  const float* W_UV  = (const float*)d_in[3];
  const float* W_DQ  = (const float*)d_in[4];
  const float* W_UQ  = (const float*)d_in[5];
  const float* W_lam = (const float*)d_in[6];
  const float* b_lam = (const float*)d_in[7];
  const float* W_out = (const float*)d_in[8];
  float* out = (float*)d_out;

  char* ws = (char*)d_ws;
  float*   c_kv = (float*)(ws);                        //  4 MB (2048x512)   f32
  float*   c_q  = (float*)(ws + ((size_t)4  << 20));   //  8 MB (2048x1024)  f32
  __bf16*  k_bf = (__bf16*)(ws + ((size_t)12 << 20));  //  8 MB (2048x2048)  bf16
  __bf16*  v_bf = (__bf16*)(ws + ((size_t)20 << 20));  //  8 MB (2048x2048)  bf16
  __bf16*  q_bf = (__bf16*)(ws + ((size_t)28 << 20));  // 16 MB (2048x4096)  bf16
  __bf16*  v_t  = (__bf16*)(ws + ((size_t)44 << 20));  //  8 MB (2048x2048)  bf16
  float*   attn = (float*)(ws + ((size_t)52 << 20));   // 32 MB (32x2048x128)f32
  float*   y    = (float*)(ws + ((size_t)84 << 20));   // 16 MB (2048x2048)  f32
  float*   lam  = (float*)(ws + ((size_t)100 << 20));  // 128 KB
  float*   cosT = (float*)(ws + ((size_t)101 << 20));  //  1 MB
  float*   sinT = (float*)(ws + ((size_t)102 << 20));  //  1 MB

  rope_table_kernel<<<2048, 128, 0, stream>>>(cosT, sinT);
  // Down-projections (fp32 out)
  gemm_t<false><<<dim3(512 / 64, 2048 / 64),  256, 0, stream>>>(x, W_DKV, c_kv, 2048, 512,  2048);
  gemm_t<false><<<dim3(1024 / 64, 2048 / 64), 256, 0, stream>>>(x, W_DQ,  c_q,  2048, 1024, 2048);
  // Up-projections (bf16 out)
  gemm_t<true><<<dim3(2048 / 64, 2048 / 64), 256, 0, stream>>>(c_kv, W_UK, k_bf, 2048, 2048, 512);
  gemm_t<true><<<dim3(2048 / 64, 2048 / 64), 256, 0, stream>>>(c_kv, W_UV, v_bf, 2048, 2048, 512);
  gemm_t<true><<<dim3(4096 / 64, 2048 / 64), 256, 0, stream>>>(c_q,  W_UQ, q_bf, 2048, 4096, 1024);
  // RoPE in-place (bf16)
  rope_bf16_kernel<<<2048, 256, 0, stream>>>(k_bf, cosT, sinT, 2048);
  rope_bf16_kernel<<<2048, 256, 0, stream>>>(q_bf, cosT, sinT, 4096);
  // V transpose to (dim, seq)
  transpose_bf16_kernel<<<dim3(64, 64), 256, 0, stream>>>(v_bf, v_t);
  // Gate
  lam_kernel<<<2048, 256, 0, stream>>>(x, W_lam, b_lam, lam);
  // MFMA flash attention
  attn_mfma_kernel<<<dim3(2048 / ATQ, 32), 256, 0, stream>>>(q_bf, k_bf, v_t, attn);
  // Differential combine
  combine_kernel<<<2048, 256, 0, stream>>>(attn, lam, y);
  // Output projection (fp32)
  gemm_t<false><<<dim3(2048 / 64, 2048 / 64), 256, 0, stream>>>(y, W_out, out, 2048, 2048, 2048);
}

// Round 3
// 697.700 us; speedup vs baseline: 5.3277x; 1.8640x over previous
//
#include <hip/hip_runtime.h>
#include <cstdint>
#include <cstddef>

typedef __bf16 bf16x8 __attribute__((ext_vector_type(8)));
typedef __bf16 bf16x4 __attribute__((ext_vector_type(4)));
typedef float f32x4 __attribute__((ext_vector_type(4)));

// ---------------------------------------------------------------------------
// Problem constants (B=1): D=2048, NH=16, DH=128, DC=512, DCQ=1024, L=2048
// ---------------------------------------------------------------------------

// ---------------------------------------------------------------------------
// MFMA GEMM: C(M,N) = A(M,K) @ Bt(N,K)^T.  A,Bt row-major bf16.
// 128x128 tile, BK=32, 4 waves, each wave 64x64 (4x4 of 16x16x32 MFMA).
// Staging via global_load_lds width=16 (wave-uniform LDS base + lane*16).
// M,N multiples of 128; K multiple of 32.
// ---------------------------------------------------------------------------
template <bool BF16OUT>
__global__ __launch_bounds__(256) void gemm_mfma(const __bf16* __restrict__ A,
                                                 const __bf16* __restrict__ Bt,
                                                 void* __restrict__ Cv,
                                                 int M, int N, int K) {
  __shared__ __bf16 As[128 * 32];  // As[m*32 + k], contiguous (no pad: lds-dma)
  __shared__ __bf16 Bs[128 * 32];  // Bs[n*32 + k]
  const int bm = blockIdx.y * 128;
  const int bn = blockIdx.x * 128;
  const int tid = threadIdx.x;
  const int w = tid >> 6;
  const int lane = tid & 63;
  const int quad = lane >> 4;
  const int l16 = lane & 15;
  const int wm = (w & 1) * 64;
  const int wn = (w >> 1) * 64;
  const int srow = lane >> 2;        // row within 16-row staging group
  const int sseg = (lane & 3) * 8;   // k-element offset (8 bf16 = 16 B)

  f32x4 acc[4][4];
#pragma unroll
  for (int i = 0; i < 4; ++i)
#pragma unroll
    for (int j = 0; j < 4; ++j) acc[i][j] = (f32x4){0.f, 0.f, 0.f, 0.f};

  for (int k0 = 0; k0 < K; k0 += 32) {
    __syncthreads();  // previous iter's ds_reads done before overwrite
#pragma unroll
    for (int g = 0; g < 2; ++g) {
      const int grp = w + g * 4;  // 0..7 (wave-uniform)
      const __bf16* ga = A + (size_t)(bm + grp * 16 + srow) * K + k0 + sseg;
      const __bf16* gb = Bt + (size_t)(bn + grp * 16 + srow) * K + k0 + sseg;
      __builtin_amdgcn_global_load_lds(
          (const __attribute__((address_space(1))) void*)ga,
          (__attribute__((address_space(3))) void*)&As[grp * 512], 16, 0, 0);
      __builtin_amdgcn_global_load_lds(
          (const __attribute__((address_space(1))) void*)gb,
          (__attribute__((address_space(3))) void*)&Bs[grp * 512], 16, 0, 0);
    }
    __syncthreads();  // drains vmcnt (lds-dma) per barrier semantics
    bf16x8 af[4], bfr[4];
#pragma unroll
    for (int i = 0; i < 4; ++i) {
      af[i] = *(const bf16x8*)&As[(wm + i * 16 + l16) * 32 + quad * 8];
      bfr[i] = *(const bf16x8*)&Bs[(wn + i * 16 + l16) * 32 + quad * 8];
    }
#pragma unroll
    for (int i = 0; i < 4; ++i)
#pragma unroll
      for (int j = 0; j < 4; ++j)
        acc[i][j] = __builtin_amdgcn_mfma_f32_16x16x32_bf16(af[i], bfr[j],
                                                            acc[i][j], 0, 0, 0);
  }
  // epilogue: C/D layout col=l16, row=quad*4+r
#pragma unroll
  for (int i = 0; i < 4; ++i)
#pragma unroll
    for (int j = 0; j < 4; ++j)
#pragma unroll
      for (int r = 0; r < 4; ++r) {
        const int row = bm + wm + i * 16 + quad * 4 + r;
        const int col = bn + wn + j * 16 + l16;
        if constexpr (BF16OUT)
          ((__bf16*)Cv)[(size_t)row * N + col] = (__bf16)acc[i][j][r];
        else
          ((float*)Cv)[(size_t)row * N + col] = acc[i][j][r];
      }
}

// fp32 (K,N) -> bf16 (N,K) transpose-cast.  Grid (K/32, N/32), 256 thr.
__global__ __launch_bounds__(256) void castT_kernel(const float* __restrict__ src,
                                                    __bf16* __restrict__ dst,
                                                    int K, int N) {
  __shared__ float T[32][36];
  const int k0 = blockIdx.x * 32;
  const int n0 = blockIdx.y * 32;
  const int r = threadIdx.x >> 3;        // 0..31
  const int c = (threadIdx.x & 7) * 4;   // 0..28
  *(float4*)&T[r][c] = *(const float4*)&src[(size_t)(k0 + r) * N + n0 + c];
  __syncthreads();
  bf16x4 o = {(__bf16)T[c + 0][r], (__bf16)T[c + 1][r],
              (__bf16)T[c + 2][r], (__bf16)T[c + 3][r]};
  *(bf16x4*)&dst[(size_t)(n0 + r) * K + k0 + c] = o;
}

// elementwise fp32 -> bf16 (n multiple of 1024)
__global__ __launch_bounds__(256) void cast_kernel(const float* __restrict__ src,
                                                   __bf16* __restrict__ dst) {
  const int i = blockIdx.x * 256 + threadIdx.x;
  float4 v = *(const float4*)&src[i * 4];
  bf16x4 o = {(__bf16)v.x, (__bf16)v.y, (__bf16)v.z, (__bf16)v.w};
  *(bf16x4*)&dst[i * 4] = o;
}

// cos/sin tables: (L, 128).  inv_freq[j] = 10000^(-j/64), j = d & 63.
__global__ void rope_table_kernel(float* __restrict__ cosT,
                                  float* __restrict__ sinT) {
  const int l = blockIdx.x;
  const int d = threadIdx.x;  // 0..127
  const int j = d & 63;
  const float inv = powf(10000.0f, -(float)j * (1.0f / 64.0f));
  const float ang = (float)l * inv;
  cosT[l * 128 + d] = cosf(ang);
  sinT[l * 128 + d] = sinf(ang);
}

// In-place RoPE on a (2048, W) row-major bf16 tensor; heads of 128 along W.
__global__ __launch_bounds__(256) void rope_bf16_kernel(__bf16* __restrict__ T,
                                                        const float* __restrict__ cosT,
                                                        const float* __restrict__ sinT,
                                                        int W) {
  __shared__ float row[4096];
  const int l = blockIdx.x;
  const int tid = threadIdx.x;
  __bf16* rp = T + (size_t)l * W;
  for (int e4 = tid; e4 * 4 < W; e4 += 256) {
    bf16x4 v = *(const bf16x4*)&rp[e4 * 4];
#pragma unroll
    for (int i = 0; i < 4; ++i) row[e4 * 4 + i] = (float)v[i];
  }
  __syncthreads();
  for (int e = tid; e < W; e += 256) {
    const int d = e & 127;
    const float c = cosT[l * 128 + d];
    const float s = sinT[l * 128 + d];
    const float t = row[e];
    const int base = e & ~127;
    const float rot = (d < 64) ? -row[base + d + 64] : row[base + d - 64];
    rp[e] = (__bf16)(t * c + rot * s);
  }
}

// (2048 l, 2048 dims) bf16  ->  (2048 dims, 2048 l) bf16
__global__ __launch_bounds__(256) void transpose_bf16_kernel(const __bf16* __restrict__ src,
                                                             __bf16* __restrict__ dst) {
  __shared__ __align__(16) __bf16 Ts[32][40];
  const int l0 = blockIdx.x * 32;
  const int d0 = blockIdx.y * 32;
  const int r = threadIdx.x >> 3;
  const int c = (threadIdx.x & 7) * 4;
  *(bf16x4*)&Ts[r][c] = *(const bf16x4*)&src[(size_t)(l0 + r) * 2048 + d0 + c];
  __syncthreads();
  bf16x4 o = {Ts[c + 0][r], Ts[c + 1][r], Ts[c + 2][r], Ts[c + 3][r]};
  *(bf16x4*)&dst[(size_t)(d0 + r) * 2048 + l0 + c] = o;
}

// lam(l,h) = sigmoid( x[l,:] . W_lam[:,h] + b_lam[h] ), one block per row l.
__global__ __launch_bounds__(256) void lam_kernel(const float* __restrict__ x,
                                                  const float* __restrict__ W_lam,
                                                  const float* __restrict__ b_lam,
                                                  float* __restrict__ lam) {
  __shared__ float xr[2048];
  __shared__ float part[16][17];
  const int l = blockIdx.x;
  const int tid = threadIdx.x;
#pragma unroll
  for (int i = 0; i < 2; ++i) {
    const int e4 = tid + 256 * i;
    *(float4*)&xr[e4 << 2] = *(const float4*)&x[(size_t)l * 2048 + (e4 << 2)];
  }
  __syncthreads();
  const int h = tid >> 4;
  const int seg = tid & 15;
  float s = 0.f;
  for (int k = seg * 128; k < seg * 128 + 128; ++k)
    s += xr[k] * W_lam[k * 16 + h];
  part[h][seg] = s;
  __syncthreads();
  if (tid < 16) {
    float t = b_lam[tid];
#pragma unroll
    for (int i = 0; i < 16; ++i) t += part[tid][i];
    lam[l * 16 + tid] = 1.0f / (1.0f + expf(-t));
  }
}

// ---------------------------------------------------------------------------
// MFMA flash attention (unchanged from round 2 — verified).
// ---------------------------------------------------------------------------
#define ATQ 64
__global__ __launch_bounds__(256) void attn_mfma_kernel(const __bf16* __restrict__ Qb,
                                                        const __bf16* __restrict__ Kb,
                                                        const __bf16* __restrict__ Vt,
                                                        float* __restrict__ O) {
  __shared__ __align__(16) __bf16 Ks[32][136];
  __shared__ __align__(16) __bf16 Vs[128][40];
  __shared__ __align__(16) __bf16 Ps[4][16][40];
  const int h32 = blockIdx.y;
  const int q0 = blockIdx.x * ATQ;
  const int tid = threadIdx.x;
  const int w = tid >> 6;
  const int lane = tid & 63;
  const int quad = lane >> 4;
  const int l16 = lane & 15;
  const int qoff = h32 * 128;
  const int kvoff = (h32 >> 1) * 128;
  const float scale = 0.08838834764831845f;

  bf16x8 aq[4];
  {
    const size_t qbase = (size_t)(q0 + w * 16 + l16) * 4096 + qoff + quad * 8;
#pragma unroll
    for (int ks = 0; ks < 4; ++ks)
      aq[ks] = *(const bf16x8*)&Qb[qbase + ks * 32];
  }

  f32x4 o[8];
#pragma unroll
  for (int i = 0; i < 8; ++i) o[i] = (f32x4){0.f, 0.f, 0.f, 0.f};
  float m[4], lsum[4];
#pragma unroll
  for (int r = 0; r < 4; ++r) { m[r] = -1e30f; lsum[r] = 0.f; }

  const int ktmax = (q0 + ATQ - 1) / 32;
  for (int kt = 0; kt <= ktmax; ++kt) {
    const int k0 = kt * 32;
    __syncthreads();
#pragma unroll
    for (int i = 0; i < 2; ++i) {
      const int f = tid + 256 * i;
      const int kr = f >> 4, seg = f & 15;
      *(bf16x8*)&Ks[kr][seg * 8] =
          *(const bf16x8*)&Kb[(size_t)(k0 + kr) * 2048 + kvoff + seg * 8];
      const int dr = f >> 2, sg2 = f & 3;
      *(bf16x8*)&Vs[dr][sg2 * 8] =
          *(const bf16x8*)&Vt[(size_t)(kvoff + dr) * 2048 + k0 + sg2 * 8];
    }
    __syncthreads();
    f32x4 s0a = (f32x4){0.f, 0.f, 0.f, 0.f};
    f32x4 s1a = (f32x4){0.f, 0.f, 0.f, 0.f};
#pragma unroll
    for (int ks = 0; ks < 4; ++ks) {
      bf16x8 bk0 = *(bf16x8*)&Ks[l16][ks * 32 + quad * 8];
      bf16x8 bk1 = *(bf16x8*)&Ks[16 + l16][ks * 32 + quad * 8];
      s0a = __builtin_amdgcn_mfma_f32_16x16x32_bf16(aq[ks], bk0, s0a, 0, 0, 0);
      s1a = __builtin_amdgcn_mfma_f32_16x16x32_bf16(aq[ks], bk1, s1a, 0, 0, 0);
    }
#pragma unroll
    for (int r = 0; r < 4; ++r) {
      const int q = q0 + w * 16 + quad * 4 + r;
      float v0 = (k0 + l16 <= q) ? s0a[r] * scale : -1e30f;
      float v1 = (k0 + 16 + l16 <= q) ? s1a[r] * scale : -1e30f;
      float rm = fmaxf(v0, v1);
#pragma unroll
      for (int off = 1; off < 16; off <<= 1)
        rm = fmaxf(rm, __shfl_xor(rm, off, 64));
      const float mn = fmaxf(m[r], rm);
      const float alpha = __expf(m[r] - mn);
      const float p0 = __expf(v0 - mn);
      const float p1 = __expf(v1 - mn);
      float rs = p0 + p1;
#pragma unroll
      for (int off = 1; off < 16; off <<= 1)
        rs += __shfl_xor(rs, off, 64);
      m[r] = mn;
      lsum[r] = lsum[r] * alpha + rs;
#pragma unroll
      for (int nt2 = 0; nt2 < 8; ++nt2) o[nt2][r] *= alpha;
      Ps[w][quad * 4 + r][l16] = (__bf16)p0;
      Ps[w][quad * 4 + r][16 + l16] = (__bf16)p1;
    }
    __syncthreads();
    bf16x8 pa = *(bf16x8*)&Ps[w][l16][quad * 8];
#pragma unroll
    for (int nt2 = 0; nt2 < 8; ++nt2) {
      bf16x8 bv = *(bf16x8*)&Vs[nt2 * 16 + l16][quad * 8];
      o[nt2] = __builtin_amdgcn_mfma_f32_16x16x32_bf16(pa, bv, o[nt2], 0, 0, 0);
    }
  }
#pragma unroll
  for (int r = 0; r < 4; ++r) {
    const float inv = 1.0f / lsum[r];
    const int q = q0 + w * 16 + quad * 4 + r;
    float* dst = O + ((size_t)h32 * 2048 + q) * 128;
#pragma unroll
    for (int nt2 = 0; nt2 < 8; ++nt2)
      dst[nt2 * 16 + l16] = o[nt2][r] * inv;
  }
}

// y[l, h*128+d] = attn[2h, l, d] - lam[l,h] * attn[2h+1, l, d]   (bf16 out)
__global__ __launch_bounds__(256) void combine_kernel(const float* __restrict__ attn,
                                                      const float* __restrict__ lam,
                                                      __bf16* __restrict__ y) {
  const int l = blockIdx.x;
  const int tid = threadIdx.x;
  const int h = tid >> 4;
  const int d = (tid & 15) * 8;
  const float lm = lam[l * 16 + h];
  const float* a1 = &attn[((size_t)(2 * h) * 2048 + l) * 128 + d];
  const float* a2 = &attn[((size_t)(2 * h + 1) * 2048 + l) * 128 + d];
  bf16x8 o;
#pragma unroll
  for (int i = 0; i < 8; ++i) o[i] = (__bf16)(a1[i] - lm * a2[i]);
  *(bf16x8*)&y[(size_t)l * 2048 + h * 128 + d] = o;
}

extern "C" void kernel_launch(void* const* d_in, const int* in_sizes, int n_in,
                              void* d_out, int out_size, void* d_ws, size_t ws_size,
                              hipStream_t stream) {
  const float* x     = (const float*)d_in[0];
  const float* W_DKV = (const float*)d_in[1];
  const float* W_UK  = (const float*)d_in[2];
  const float* W_UV  = (const float*)d_in[3];
  const float* W_DQ  = (const float*)d_in[4];
  const float* W_UQ  = (const float*)d_in[5];
  const float* W_lam = (const float*)d_in[6];
  const float* b_lam = (const float*)d_in[7];
  const float* W_out = (const float*)d_in[8];
  float* out = (float*)d_out;

  char* ws = (char*)d_ws;
  #define MB(n) ((size_t)(n) << 20)
  __bf16* x_bf   = (__bf16*)(ws + MB(0));    //  8 MB (2048x2048)
  __bf16* Wt_out = (__bf16*)(ws + MB(0));    //  8 MB alias: x_bf dead after down-proj
  __bf16* Wt_DKV = (__bf16*)(ws + MB(8));    //  2 MB (512x2048)
  __bf16* Wt_DQ  = (__bf16*)(ws + MB(10));   //  4 MB (1024x2048)
  __bf16* c_kv   = (__bf16*)(ws + MB(14));   //  2 MB (2048x512)
  __bf16* c_q    = (__bf16*)(ws + MB(16));   //  4 MB (2048x1024)
  __bf16* Wt_UK  = (__bf16*)(ws + MB(20));   //  2 MB (2048x512)
  __bf16* Wt_UV  = (__bf16*)(ws + MB(22));   //  2 MB (2048x512)
  __bf16* Wt_UQ  = (__bf16*)(ws + MB(24));   //  8 MB (4096x1024)
  __bf16* k_bf   = (__bf16*)(ws + MB(32));   //  8 MB (2048x2048)
  __bf16* v_bf   = (__bf16*)(ws + MB(40));   //  8 MB (2048x2048)
  __bf16* y_bf   = (__bf16*)(ws + MB(40));   //  8 MB alias: v_bf dead after v_t
  __bf16* q_bf   = (__bf16*)(ws + MB(48));   // 16 MB (2048x4096)
  __bf16* v_t    = (__bf16*)(ws + MB(64));   //  8 MB (2048x2048)
  float*  attn   = (float*)(ws + MB(72));    // 32 MB (32x2048x128)
  float*  lam    = (float*)(ws + MB(104));   // 128 KB
  float*  cosT   = (float*)(ws + MB(105));   //  1 MB
  float*  sinT   = (float*)(ws + MB(106));   //  1 MB  (total 107 MB)

  rope_table_kernel<<<2048, 128, 0, stream>>>(cosT, sinT);
  // casts / transposes of inputs
  cast_kernel<<<4096, 256, 0, stream>>>(x, x_bf);
  castT_kernel<<<dim3(64, 16), 256, 0, stream>>>(W_DKV, Wt_DKV, 2048, 512);
  castT_kernel<<<dim3(64, 32), 256, 0, stream>>>(W_DQ,  Wt_DQ,  2048, 1024);
  castT_kernel<<<dim3(16, 64), 256, 0, stream>>>(W_UK,  Wt_UK,  512,  2048);
  castT_kernel<<<dim3(16, 64), 256, 0, stream>>>(W_UV,  Wt_UV,  512,  2048);
  castT_kernel<<<dim3(32, 128), 256, 0, stream>>>(W_UQ, Wt_UQ,  1024, 4096);
  // down-projections (bf16 out)
  gemm_mfma<true><<<dim3(4, 16),  256, 0, stream>>>(x_bf, Wt_DKV, c_kv, 2048, 512,  2048);
  gemm_mfma<true><<<dim3(8, 16),  256, 0, stream>>>(x_bf, Wt_DQ,  c_q,  2048, 1024, 2048);
  // W_out transpose into x_bf region (x_bf now dead)
  castT_kernel<<<dim3(64, 64), 256, 0, stream>>>(W_out, Wt_out, 2048, 2048);
  // up-projections (bf16 out)
  gemm_mfma<true><<<dim3(16, 16), 256, 0, stream>>>(c_kv, Wt_UK, k_bf, 2048, 2048, 512);
  gemm_mfma<true><<<dim3(16, 16), 256, 0, stream>>>(c_kv, Wt_UV, v_bf, 2048, 2048, 512);
  gemm_mfma<true><<<dim3(32, 16), 256, 0, stream>>>(c_q,  Wt_UQ, q_bf, 2048, 4096, 1024);
  // RoPE in-place (bf16)
  rope_bf16_kernel<<<2048, 256, 0, stream>>>(k_bf, cosT, sinT, 2048);
  rope_bf16_kernel<<<2048, 256, 0, stream>>>(q_bf, cosT, sinT, 4096);
  // V transpose to (dim, seq)
  transpose_bf16_kernel<<<dim3(64, 64), 256, 0, stream>>>(v_bf, v_t);
  // Gate
  lam_kernel<<<2048, 256, 0, stream>>>(x, W_lam, b_lam, lam);
  // MFMA flash attention
  attn_mfma_kernel<<<dim3(2048 / ATQ, 32), 256, 0, stream>>>(q_bf, k_bf, v_t, attn);
  // Differential combine (bf16 y)
  combine_kernel<<<2048, 256, 0, stream>>>(attn, lam, y_bf);
  // Output projection (fp32 out)
  gemm_mfma<false><<<dim3(16, 16), 256, 0, stream>>>(y_bf, Wt_out, out, 2048, 2048, 2048);
}

// Round 4
// 600.999 us; speedup vs baseline: 6.1849x; 1.1609x over previous
//
#include <hip/hip_runtime.h>
#include <cstdint>
#include <cstddef>

typedef __bf16 bf16x8 __attribute__((ext_vector_type(8)));
typedef __bf16 bf16x4 __attribute__((ext_vector_type(4)));
typedef float f32x4 __attribute__((ext_vector_type(4)));

// ---------------------------------------------------------------------------
// Problem constants (B=1): D=2048, NH=16, DH=128, DC=512, DCQ=1024, L=2048
// ---------------------------------------------------------------------------

// ---------------------------------------------------------------------------
// MFMA GEMM: C(M,N) = A(M,K) @ Bt(N,K)^T.  A,Bt row-major bf16.
// 128x128 tile, BK=32, 4 waves, each wave 64x64 (4x4 of 16x16x32 MFMA).
// ---------------------------------------------------------------------------
template <bool BF16OUT>
__global__ __launch_bounds__(256) void gemm_mfma(const __bf16* __restrict__ A,
                                                 const __bf16* __restrict__ Bt,
                                                 void* __restrict__ Cv,
                                                 int M, int N, int K) {
  __shared__ __bf16 As[128 * 32];  // As[m*32 + k], contiguous (no pad: lds-dma)
  __shared__ __bf16 Bs[128 * 32];  // Bs[n*32 + k]
  const int bm = blockIdx.y * 128;
  const int bn = blockIdx.x * 128;
  const int tid = threadIdx.x;
  const int w = tid >> 6;
  const int lane = tid & 63;
  const int quad = lane >> 4;
  const int l16 = lane & 15;
  const int wm = (w & 1) * 64;
  const int wn = (w >> 1) * 64;
  const int srow = lane >> 2;
  const int sseg = (lane & 3) * 8;

  f32x4 acc[4][4];
#pragma unroll
  for (int i = 0; i < 4; ++i)
#pragma unroll
    for (int j = 0; j < 4; ++j) acc[i][j] = (f32x4){0.f, 0.f, 0.f, 0.f};

  for (int k0 = 0; k0 < K; k0 += 32) {
    __syncthreads();
#pragma unroll
    for (int g = 0; g < 2; ++g) {
      const int grp = w + g * 4;
      const __bf16* ga = A + (size_t)(bm + grp * 16 + srow) * K + k0 + sseg;
      const __bf16* gb = Bt + (size_t)(bn + grp * 16 + srow) * K + k0 + sseg;
      __builtin_amdgcn_global_load_lds(
          (const __attribute__((address_space(1))) void*)ga,
          (__attribute__((address_space(3))) void*)&As[grp * 512], 16, 0, 0);
      __builtin_amdgcn_global_load_lds(
          (const __attribute__((address_space(1))) void*)gb,
          (__attribute__((address_space(3))) void*)&Bs[grp * 512], 16, 0, 0);
    }
    __syncthreads();
    bf16x8 af[4], bfr[4];
#pragma unroll
    for (int i = 0; i < 4; ++i) {
      af[i] = *(const bf16x8*)&As[(wm + i * 16 + l16) * 32 + quad * 8];
      bfr[i] = *(const bf16x8*)&Bs[(wn + i * 16 + l16) * 32 + quad * 8];
    }
#pragma unroll
    for (int i = 0; i < 4; ++i)
#pragma unroll
      for (int j = 0; j < 4; ++j)
        acc[i][j] = __builtin_amdgcn_mfma_f32_16x16x32_bf16(af[i], bfr[j],
                                                            acc[i][j], 0, 0, 0);
  }
#pragma unroll
  for (int i = 0; i < 4; ++i)
#pragma unroll
    for (int j = 0; j < 4; ++j)
#pragma unroll
      for (int r = 0; r < 4; ++r) {
        const int row = bm + wm + i * 16 + quad * 4 + r;
        const int col = bn + wn + j * 16 + l16;
        if constexpr (BF16OUT)
          ((__bf16*)Cv)[(size_t)row * N + col] = (__bf16)acc[i][j][r];
        else
          ((float*)Cv)[(size_t)row * N + col] = acc[i][j][r];
      }
}

// fp32 (K,N) -> bf16 (N,K) transpose-cast.  Grid (K/32, N/32), 256 thr.
__global__ __launch_bounds__(256) void castT_kernel(const float* __restrict__ src,
                                                    __bf16* __restrict__ dst,
                                                    int K, int N) {
  __shared__ float T[32][36];
  const int k0 = blockIdx.x * 32;
  const int n0 = blockIdx.y * 32;
  const int r = threadIdx.x >> 3;
  const int c = (threadIdx.x & 7) * 4;
  *(float4*)&T[r][c] = *(const float4*)&src[(size_t)(k0 + r) * N + n0 + c];
  __syncthreads();
  bf16x4 o = {(__bf16)T[c + 0][r], (__bf16)T[c + 1][r],
              (__bf16)T[c + 2][r], (__bf16)T[c + 3][r]};
  *(bf16x4*)&dst[(size_t)(n0 + r) * K + k0 + c] = o;
}

// elementwise fp32 -> bf16 (n multiple of 1024)
__global__ __launch_bounds__(256) void cast_kernel(const float* __restrict__ src,
                                                   __bf16* __restrict__ dst) {
  const int i = blockIdx.x * 256 + threadIdx.x;
  float4 v = *(const float4*)&src[i * 4];
  bf16x4 o = {(__bf16)v.x, (__bf16)v.y, (__bf16)v.z, (__bf16)v.w};
  *(bf16x4*)&dst[i * 4] = o;
}

// cos/sin tables: (L, 128).  inv_freq[j] = 10000^(-j/64), j = d & 63.
__global__ void rope_table_kernel(float* __restrict__ cosT,
                                  float* __restrict__ sinT) {
  const int l = blockIdx.x;
  const int d = threadIdx.x;
  const int j = d & 63;
  const float inv = powf(10000.0f, -(float)j * (1.0f / 64.0f));
  const float ang = (float)l * inv;
  cosT[l * 128 + d] = cosf(ang);
  sinT[l * 128 + d] = sinf(ang);
}

// In-place RoPE on a (2048, W) row-major bf16 tensor; heads of 128 along W.
__global__ __launch_bounds__(256) void rope_bf16_kernel(__bf16* __restrict__ T,
                                                        const float* __restrict__ cosT,
                                                        const float* __restrict__ sinT,
                                                        int W) {
  __shared__ float row[4096];
  const int l = blockIdx.x;
  const int tid = threadIdx.x;
  __bf16* rp = T + (size_t)l * W;
  for (int e4 = tid; e4 * 4 < W; e4 += 256) {
    bf16x4 v = *(const bf16x4*)&rp[e4 * 4];
#pragma unroll
    for (int i = 0; i < 4; ++i) row[e4 * 4 + i] = (float)v[i];
  }
  __syncthreads();
  for (int e = tid; e < W; e += 256) {
    const int d = e & 127;
    const float c = cosT[l * 128 + d];
    const float s = sinT[l * 128 + d];
    const float t = row[e];
    const int base = e & ~127;
    const float rot = (d < 64) ? -row[base + d + 64] : row[base + d - 64];
    rp[e] = (__bf16)(t * c + rot * s);
  }
}

// (2048 l, 2048 dims) bf16  ->  (2048 dims, 2048 l) bf16
__global__ __launch_bounds__(256) void transpose_bf16_kernel(const __bf16* __restrict__ src,
                                                             __bf16* __restrict__ dst) {
  __shared__ __align__(16) __bf16 Ts[32][40];
  const int l0 = blockIdx.x * 32;
  const int d0 = blockIdx.y * 32;
  const int r = threadIdx.x >> 3;
  const int c = (threadIdx.x & 7) * 4;
  *(bf16x4*)&Ts[r][c] = *(const bf16x4*)&src[(size_t)(l0 + r) * 2048 + d0 + c];
  __syncthreads();
  bf16x4 o = {Ts[c + 0][r], Ts[c + 1][r], Ts[c + 2][r], Ts[c + 3][r]};
  *(bf16x4*)&dst[(size_t)(d0 + r) * 2048 + l0 + c] = o;
}

// lam(l,h) = sigmoid( x[l,:] . W_lam[:,h] + b_lam[h] ), one block per row l.
__global__ __launch_bounds__(256) void lam_kernel(const float* __restrict__ x,
                                                  const float* __restrict__ W_lam,
                                                  const float* __restrict__ b_lam,
                                                  float* __restrict__ lam) {
  __shared__ float xr[2048];
  __shared__ float part[16][17];
  const int l = blockIdx.x;
  const int tid = threadIdx.x;
#pragma unroll
  for (int i = 0; i < 2; ++i) {
    const int e4 = tid + 256 * i;
    *(float4*)&xr[e4 << 2] = *(const float4*)&x[(size_t)l * 2048 + (e4 << 2)];
  }
  __syncthreads();
  const int h = tid >> 4;
  const int seg = tid & 15;
  float s = 0.f;
  for (int k = seg * 128; k < seg * 128 + 128; ++k)
    s += xr[k] * W_lam[k * 16 + h];
  part[h][seg] = s;
  __syncthreads();
  if (tid < 16) {
    float t = b_lam[tid];
#pragma unroll
    for (int i = 0; i < 16; ++i) t += part[tid][i];
    lam[l * 16 + tid] = 1.0f / (1.0f + expf(-t));
  }
}

// ---------------------------------------------------------------------------
// MFMA flash attention, transposed-score softmax.
//  Qb: (2048, 4096) roped bf16 (32 q-heads).  Kb: (2048, 2048) roped bf16.
//  Vt: (2048 dims, 2048 l) bf16.  O: (32, 2048, 128) f32.
//  Block: 4 waves; wave w owns Q rows q0+w*16..+15; K-tile 64.
//  S^T = K·Q^T via operand swap: lane owns q-row l16, keys t*16+quad*4+r.
// ---------------------------------------------------------------------------
#define ATQ 64
__global__ __launch_bounds__(256) void attn_mfma_kernel(const __bf16* __restrict__ Qb,
                                                        const __bf16* __restrict__ Kb,
                                                        const __bf16* __restrict__ Vt,
                                                        float* __restrict__ O) {
  __shared__ __align__(16) __bf16 Ks[64][136];   // (key, dim) padded
  __shared__ __align__(16) __bf16 Vs[128][72];   // (dim, key) padded
  __shared__ __align__(16) __bf16 Ps[4][16][72]; // per-wave P (qrow, key)
  const int h32 = blockIdx.y;
  const int qt = (int)gridDim.x - 1 - (int)blockIdx.x;  // heavy tiles first
  const int q0 = qt * ATQ;
  const int tid = threadIdx.x;
  const int w = tid >> 6;
  const int lane = tid & 63;
  const int quad = lane >> 4;
  const int l16 = lane & 15;
  const int qoff = h32 * 128;
  const int kvoff = (h32 >> 1) * 128;
  const float scale = 0.08838834764831845f;  // 1/sqrt(128)
  const int q = q0 + w * 16 + l16;           // q-row owned by this lane

  // Q fragments: B-operand for S^T (and A-layout for row l16)
  bf16x8 aq[4];
  {
    const size_t qbase = (size_t)q * 4096 + qoff + quad * 8;
#pragma unroll
    for (int ks = 0; ks < 4; ++ks)
      aq[ks] = *(const bf16x8*)&Qb[qbase + ks * 32];
  }

  f32x4 o[8];
#pragma unroll
  for (int i = 0; i < 8; ++i) o[i] = (f32x4){0.f, 0.f, 0.f, 0.f};
  float m = -1e30f, lsum = 0.f;  // state for q-row l16 (replicated over quads)

  for (int kt = 0; kt <= qt; ++kt) {
    const int k0 = kt * 64;
    __syncthreads();  // prev iter's MFMA reads of Ks/Vs done
    // ---- stage K (64x128) and V^T (128x64) ----
#pragma unroll
    for (int i = 0; i < 4; ++i) {
      const int f = tid + 256 * i;             // 0..1023
      const int kr = f >> 4, seg = f & 15;
      *(bf16x8*)&Ks[kr][seg * 8] =
          *(const bf16x8*)&Kb[(size_t)(k0 + kr) * 2048 + kvoff + seg * 8];
      const int dr = f >> 3, sg = f & 7;
      *(bf16x8*)&Vs[dr][sg * 8] =
          *(const bf16x8*)&Vt[(size_t)(kvoff + dr) * 2048 + k0 + sg * 8];
    }
    __syncthreads();
    // ---- S^T = K Q^T : 4 key m-tiles x 4 k-steps ----
    f32x4 st[4];
#pragma unroll
    for (int t = 0; t < 4; ++t) st[t] = (f32x4){0.f, 0.f, 0.f, 0.f};
#pragma unroll
    for (int ks = 0; ks < 4; ++ks) {
#pragma unroll
      for (int t = 0; t < 4; ++t) {
        bf16x8 ak = *(bf16x8*)&Ks[t * 16 + l16][ks * 32 + quad * 8];
        st[t] = __builtin_amdgcn_mfma_f32_16x16x32_bf16(ak, aq[ks], st[t], 0, 0, 0);
      }
    }
    // ---- online softmax: lane owns q-row l16, 16 keys in regs ----
    float vals[16];
    float rm = -1e30f;
    if (kt < qt) {  // full tile, no masking (uniform branch)
#pragma unroll
      for (int t = 0; t < 4; ++t)
#pragma unroll
        for (int r = 0; r < 4; ++r) {
          const float v = st[t][r] * scale;
          vals[t * 4 + r] = v;
          rm = fmaxf(rm, v);
        }
    } else {  // diagonal tile
#pragma unroll
      for (int t = 0; t < 4; ++t)
#pragma unroll
        for (int r = 0; r < 4; ++r) {
          const int key = k0 + t * 16 + quad * 4 + r;
          const float v = (key <= q) ? st[t][r] * scale : -1e30f;
          vals[t * 4 + r] = v;
          rm = fmaxf(rm, v);
        }
    }
    rm = fmaxf(rm, __shfl_xor(rm, 16, 64));
    rm = fmaxf(rm, __shfl_xor(rm, 32, 64));
    const float mn = fmaxf(m, rm);
    const float alpha = __expf(m - mn);
    float rs = 0.f;
#pragma unroll
    for (int i = 0; i < 16; ++i) {
      vals[i] = __expf(vals[i] - mn);
      rs += vals[i];
    }
    rs += __shfl_xor(rs, 16, 64);
    rs += __shfl_xor(rs, 32, 64);
    m = mn;
    lsum = lsum * alpha + rs;
    // write P^T->P into per-wave LDS (packed b64 writes)
#pragma unroll
    for (int t = 0; t < 4; ++t) {
      bf16x4 pk = {(__bf16)vals[t * 4 + 0], (__bf16)vals[t * 4 + 1],
                   (__bf16)vals[t * 4 + 2], (__bf16)vals[t * 4 + 3]};
      *(bf16x4*)&Ps[w][l16][t * 16 + quad * 4] = pk;
    }
    // rescale O (alpha per row quad*4+r fetched from lane quad*4+r)
#pragma unroll
    for (int r = 0; r < 4; ++r) {
      const float ar = __shfl(alpha, quad * 4 + r, 64);
#pragma unroll
      for (int nt = 0; nt < 8; ++nt) o[nt][r] *= ar;
    }
    // ---- O += P V : 2 k-steps x 8 dim-tiles (per-wave P, no barrier) ----
#pragma unroll
    for (int ks = 0; ks < 2; ++ks) {
      bf16x8 pa = *(bf16x8*)&Ps[w][l16][ks * 32 + quad * 8];
#pragma unroll
      for (int nt = 0; nt < 8; ++nt) {
        bf16x8 bv = *(bf16x8*)&Vs[nt * 16 + l16][ks * 32 + quad * 8];
        o[nt] = __builtin_amdgcn_mfma_f32_16x16x32_bf16(pa, bv, o[nt], 0, 0, 0);
      }
    }
  }
  // ---- epilogue: O rows = quad*4+r, cols = nt*16+l16 ----
  const float linv = 1.0f / lsum;
#pragma unroll
  for (int r = 0; r < 4; ++r) {
    const float inv = __shfl(linv, quad * 4 + r, 64);
    const int row = q0 + w * 16 + quad * 4 + r;
    float* dst = O + ((size_t)h32 * 2048 + row) * 128;
#pragma unroll
    for (int nt = 0; nt < 8; ++nt)
      dst[nt * 16 + l16] = o[nt][r] * inv;
  }
}

// y[l, h*128+d] = attn[2h, l, d] - lam[l,h] * attn[2h+1, l, d]   (bf16 out)
__global__ __launch_bounds__(256) void combine_kernel(const float* __restrict__ attn,
                                                      const float* __restrict__ lam,
                                                      __bf16* __restrict__ y) {
  const int l = blockIdx.x;
  const int tid = threadIdx.x;
  const int h = tid >> 4;
  const int d = (tid & 15) * 8;
  const float lm = lam[l * 16 + h];
  const float* a1 = &attn[((size_t)(2 * h) * 2048 + l) * 128 + d];
  const float* a2 = &attn[((size_t)(2 * h + 1) * 2048 + l) * 128 + d];
  bf16x8 o;
#pragma unroll
  for (int i = 0; i < 8; ++i) o[i] = (__bf16)(a1[i] - lm * a2[i]);
  *(bf16x8*)&y[(size_t)l * 2048 + h * 128 + d] = o;
}

extern "C" void kernel_launch(void* const* d_in, const int* in_sizes, int n_in,
                              void* d_out, int out_size, void* d_ws, size_t ws_size,
                              hipStream_t stream) {
  const float* x     = (const float*)d_in[0];
  const float* W_DKV = (const float*)d_in[1];
  const float* W_UK  = (const float*)d_in[2];
  const float* W_UV  = (const float*)d_in[3];
  const float* W_DQ  = (const float*)d_in[4];
  const float* W_UQ  = (const float*)d_in[5];
  const float* W_lam = (const float*)d_in[6];
  const float* b_lam = (const float*)d_in[7];
  const float* W_out = (const float*)d_in[8];
  float* out = (float*)d_out;

  char* ws = (char*)d_ws;
  #define MB(n) ((size_t)(n) << 20)
  __bf16* x_bf   = (__bf16*)(ws + MB(0));    //  8 MB (2048x2048)
  __bf16* Wt_out = (__bf16*)(ws + MB(0));    //  8 MB alias: x_bf dead after down-proj
  __bf16* Wt_DKV = (__bf16*)(ws + MB(8));    //  2 MB (512x2048)
  __bf16* Wt_DQ  = (__bf16*)(ws + MB(10));   //  4 MB (1024x2048)
  __bf16* c_kv   = (__bf16*)(ws + MB(14));   //  2 MB (2048x512)
  __bf16* c_q    = (__bf16*)(ws + MB(16));   //  4 MB (2048x1024)
  __bf16* Wt_UK  = (__bf16*)(ws + MB(20));   //  2 MB (2048x512)
  __bf16* Wt_UV  = (__bf16*)(ws + MB(22));   //  2 MB (2048x512)
  __bf16* Wt_UQ  = (__bf16*)(ws + MB(24));   //  8 MB (4096x1024)
  __bf16* k_bf   = (__bf16*)(ws + MB(32));   //  8 MB (2048x2048)
  __bf16* v_bf   = (__bf16*)(ws + MB(40));   //  8 MB (2048x2048)
  __bf16* y_bf   = (__bf16*)(ws + MB(40));   //  8 MB alias: v_bf dead after v_t
  __bf16* q_bf   = (__bf16*)(ws + MB(48));   // 16 MB (2048x4096)
  __bf16* v_t    = (__bf16*)(ws + MB(64));   //  8 MB (2048x2048)
  float*  attn   = (float*)(ws + MB(72));    // 32 MB (32x2048x128)
  float*  lam    = (float*)(ws + MB(104));   // 128 KB
  float*  cosT   = (float*)(ws + MB(105));   //  1 MB
  float*  sinT   = (float*)(ws + MB(106));   //  1 MB  (total 107 MB)

  rope_table_kernel<<<2048, 128, 0, stream>>>(cosT, sinT);
  cast_kernel<<<4096, 256, 0, stream>>>(x, x_bf);
  castT_kernel<<<dim3(64, 16), 256, 0, stream>>>(W_DKV, Wt_DKV, 2048, 512);
  castT_kernel<<<dim3(64, 32), 256, 0, stream>>>(W_DQ,  Wt_DQ,  2048, 1024);
  castT_kernel<<<dim3(16, 64), 256, 0, stream>>>(W_UK,  Wt_UK,  512,  2048);
  castT_kernel<<<dim3(16, 64), 256, 0, stream>>>(W_UV,  Wt_UV,  512,  2048);
  castT_kernel<<<dim3(32, 128), 256, 0, stream>>>(W_UQ, Wt_UQ,  1024, 4096);
  gemm_mfma<true><<<dim3(4, 16),  256, 0, stream>>>(x_bf, Wt_DKV, c_kv, 2048, 512,  2048);
  gemm_mfma<true><<<dim3(8, 16),  256, 0, stream>>>(x_bf, Wt_DQ,  c_q,  2048, 1024, 2048);
  castT_kernel<<<dim3(64, 64), 256, 0, stream>>>(W_out, Wt_out, 2048, 2048);
  gemm_mfma<true><<<dim3(16, 16), 256, 0, stream>>>(c_kv, Wt_UK, k_bf, 2048, 2048, 512);
  gemm_mfma<true><<<dim3(16, 16), 256, 0, stream>>>(c_kv, Wt_UV, v_bf, 2048, 2048, 512);
  gemm_mfma<true><<<dim3(32, 16), 256, 0, stream>>>(c_q,  Wt_UQ, q_bf, 2048, 4096, 1024);
  rope_bf16_kernel<<<2048, 256, 0, stream>>>(k_bf, cosT, sinT, 2048);
  rope_bf16_kernel<<<2048, 256, 0, stream>>>(q_bf, cosT, sinT, 4096);
  transpose_bf16_kernel<<<dim3(64, 64), 256, 0, stream>>>(v_bf, v_t);
  lam_kernel<<<2048, 256, 0, stream>>>(x, W_lam, b_lam, lam);
  attn_mfma_kernel<<<dim3(2048 / ATQ, 32), 256, 0, stream>>>(q_bf, k_bf, v_t, attn);
  combine_kernel<<<2048, 256, 0, stream>>>(attn, lam, y_bf);
  gemm_mfma<false><<<dim3(16, 16), 256, 0, stream>>>(y_bf, Wt_out, out, 2048, 2048, 2048);
}

// Round 5
// 510.266 us; speedup vs baseline: 7.2847x; 1.1778x over previous
//
#include <hip/hip_runtime.h>
#include <cstdint>
#include <cstddef>

typedef __bf16 bf16x8 __attribute__((ext_vector_type(8)));
typedef __bf16 bf16x4 __attribute__((ext_vector_type(4)));
typedef float f32x4 __attribute__((ext_vector_type(4)));

// ---------------------------------------------------------------------------
// Problem constants (B=1): D=2048, NH=16, DH=128, DC=512, DCQ=1024, L=2048
// ---------------------------------------------------------------------------

// ---------------------------------------------------------------------------
// MFMA GEMM core: C(M,N) = A(M,K) @ Bt(N,K)^T.  A,Bt row-major bf16.
// 128x128 tile, BK=32, 4 waves, each wave 64x64 (4x4 of 16x16x32 MFMA).
// ---------------------------------------------------------------------------
template <bool BF16OUT>
__device__ __forceinline__ void gemm_body(const __bf16* __restrict__ A,
                                          const __bf16* __restrict__ Bt,
                                          void* __restrict__ Cv,
                                          int N, int K, int bm, int bn,
                                          __bf16* As, __bf16* Bs) {
  const int tid = threadIdx.x;
  const int w = tid >> 6;
  const int lane = tid & 63;
  const int quad = lane >> 4;
  const int l16 = lane & 15;
  const int wm = (w & 1) * 64;
  const int wn = (w >> 1) * 64;
  const int srow = lane >> 2;
  const int sseg = (lane & 3) * 8;

  f32x4 acc[4][4];
#pragma unroll
  for (int i = 0; i < 4; ++i)
#pragma unroll
    for (int j = 0; j < 4; ++j) acc[i][j] = (f32x4){0.f, 0.f, 0.f, 0.f};

  for (int k0 = 0; k0 < K; k0 += 32) {
    __syncthreads();
#pragma unroll
    for (int g = 0; g < 2; ++g) {
      const int grp = w + g * 4;
      const __bf16* ga = A + (size_t)(bm + grp * 16 + srow) * K + k0 + sseg;
      const __bf16* gb = Bt + (size_t)(bn + grp * 16 + srow) * K + k0 + sseg;
      __builtin_amdgcn_global_load_lds(
          (const __attribute__((address_space(1))) void*)ga,
          (__attribute__((address_space(3))) void*)&As[grp * 512], 16, 0, 0);
      __builtin_amdgcn_global_load_lds(
          (const __attribute__((address_space(1))) void*)gb,
          (__attribute__((address_space(3))) void*)&Bs[grp * 512], 16, 0, 0);
    }
    __syncthreads();
    bf16x8 af[4], bfr[4];
#pragma unroll
    for (int i = 0; i < 4; ++i) {
      af[i] = *(const bf16x8*)&As[(wm + i * 16 + l16) * 32 + quad * 8];
      bfr[i] = *(const bf16x8*)&Bs[(wn + i * 16 + l16) * 32 + quad * 8];
    }
#pragma unroll
    for (int i = 0; i < 4; ++i)
#pragma unroll
      for (int j = 0; j < 4; ++j)
        acc[i][j] = __builtin_amdgcn_mfma_f32_16x16x32_bf16(af[i], bfr[j],
                                                            acc[i][j], 0, 0, 0);
  }
#pragma unroll
  for (int i = 0; i < 4; ++i)
#pragma unroll
    for (int j = 0; j < 4; ++j)
#pragma unroll
      for (int r = 0; r < 4; ++r) {
        const int row = bm + wm + i * 16 + quad * 4 + r;
        const int col = bn + wn + j * 16 + l16;
        if constexpr (BF16OUT)
          ((__bf16*)Cv)[(size_t)row * N + col] = (__bf16)acc[i][j][r];
        else
          ((float*)Cv)[(size_t)row * N + col] = acc[i][j][r];
      }
}

template <bool BF16OUT>
__global__ __launch_bounds__(256) void gemm_mfma(const __bf16* __restrict__ A,
                                                 const __bf16* __restrict__ Bt,
                                                 void* __restrict__ Cv,
                                                 int M, int N, int K) {
  __shared__ __bf16 As[128 * 32];
  __shared__ __bf16 Bs[128 * 32];
  gemm_body<BF16OUT>(A, Bt, Cv, N, K, blockIdx.y * 128, blockIdx.x * 128, As, Bs);
}

// Up to 3 independent GEMMs fused by blockIdx.x ranges [0,nx0), [nx0,nx0+nx1), rest.
__global__ __launch_bounds__(256) void gemm_fused3(
    const __bf16* A0, const __bf16* B0, __bf16* C0, int N0, int K0, int nx0,
    const __bf16* A1, const __bf16* B1, __bf16* C1, int N1, int K1, int nx1,
    const __bf16* A2, const __bf16* B2, __bf16* C2, int N2, int K2) {
  __shared__ __bf16 As[128 * 32];
  __shared__ __bf16 Bs[128 * 32];
  const int bx = blockIdx.x;
  const __bf16 *A, *Bt;
  __bf16* C;
  int N, K, bxl;
  if (bx < nx0)            { A = A0; Bt = B0; C = C0; N = N0; K = K0; bxl = bx; }
  else if (bx < nx0 + nx1) { A = A1; Bt = B1; C = C1; N = N1; K = K1; bxl = bx - nx0; }
  else                     { A = A2; Bt = B2; C = C2; N = N2; K = K2; bxl = bx - nx0 - nx1; }
  gemm_body<true>(A, Bt, (void*)C, N, K, blockIdx.y * 128, bxl * 128, As, Bs);
}

// fp32 (K,N) -> bf16 (N,K) transpose-cast.  Grid (K/32, N/32), 256 thr.
__global__ __launch_bounds__(256) void castT_kernel(const float* __restrict__ src,
                                                    __bf16* __restrict__ dst,
                                                    int K, int N) {
  __shared__ float T[32][36];
  const int k0 = blockIdx.x * 32;
  const int n0 = blockIdx.y * 32;
  const int r = threadIdx.x >> 3;
  const int c = (threadIdx.x & 7) * 4;
  *(float4*)&T[r][c] = *(const float4*)&src[(size_t)(k0 + r) * N + n0 + c];
  __syncthreads();
  bf16x4 o = {(__bf16)T[c + 0][r], (__bf16)T[c + 1][r],
              (__bf16)T[c + 2][r], (__bf16)T[c + 3][r]};
  *(bf16x4*)&dst[(size_t)(n0 + r) * K + k0 + c] = o;
}

// elementwise fp32 -> bf16 (n multiple of 1024)
__global__ __launch_bounds__(256) void cast_kernel(const float* __restrict__ src,
                                                   __bf16* __restrict__ dst) {
  const int i = blockIdx.x * 256 + threadIdx.x;
  float4 v = *(const float4*)&src[i * 4];
  bf16x4 o = {(__bf16)v.x, (__bf16)v.y, (__bf16)v.z, (__bf16)v.w};
  *(bf16x4*)&dst[i * 4] = o;
}

// cos/sin tables: (L, 128).  inv_freq[j] = 10000^(-j/64), j = d & 63.
__global__ void rope_table_kernel(float* __restrict__ cosT,
                                  float* __restrict__ sinT) {
  const int l = blockIdx.x;
  const int d = threadIdx.x;
  const int j = d & 63;
  const float inv = powf(10000.0f, -(float)j * (1.0f / 64.0f));
  const float ang = (float)l * inv;
  cosT[l * 128 + d] = cosf(ang);
  sinT[l * 128 + d] = sinf(ang);
}

// In-place RoPE on a (2048, W) row-major bf16 tensor; heads of 128 along W.
__global__ __launch_bounds__(256) void rope_bf16_kernel(__bf16* __restrict__ T,
                                                        const float* __restrict__ cosT,
                                                        const float* __restrict__ sinT,
                                                        int W) {
  __shared__ float row[4096];
  const int l = blockIdx.x;
  const int tid = threadIdx.x;
  __bf16* rp = T + (size_t)l * W;
  for (int e4 = tid; e4 * 4 < W; e4 += 256) {
    bf16x4 v = *(const bf16x4*)&rp[e4 * 4];
#pragma unroll
    for (int i = 0; i < 4; ++i) row[e4 * 4 + i] = (float)v[i];
  }
  __syncthreads();
  for (int e = tid; e < W; e += 256) {
    const int d = e & 127;
    const float c = cosT[l * 128 + d];
    const float s = sinT[l * 128 + d];
    const float t = row[e];
    const int base = e & ~127;
    const float rot = (d < 64) ? -row[base + d + 64] : row[base + d - 64];
    rp[e] = (__bf16)(t * c + rot * s);
  }
}

// (2048 l, 2048 dims) bf16  ->  (2048 dims, 2048 l) bf16
__global__ __launch_bounds__(256) void transpose_bf16_kernel(const __bf16* __restrict__ src,
                                                             __bf16* __restrict__ dst) {
  __shared__ __align__(16) __bf16 Ts[32][40];
  const int l0 = blockIdx.x * 32;
  const int d0 = blockIdx.y * 32;
  const int r = threadIdx.x >> 3;
  const int c = (threadIdx.x & 7) * 4;
  *(bf16x4*)&Ts[r][c] = *(const bf16x4*)&src[(size_t)(l0 + r) * 2048 + d0 + c];
  __syncthreads();
  bf16x4 o = {Ts[c + 0][r], Ts[c + 1][r], Ts[c + 2][r], Ts[c + 3][r]};
  *(bf16x4*)&dst[(size_t)(d0 + r) * 2048 + l0 + c] = o;
}

// lam(l,h) = sigmoid( x[l,:] . W_lam[:,h] + b_lam[h] ), one block per row l.
__global__ __launch_bounds__(256) void lam_kernel(const float* __restrict__ x,
                                                  const float* __restrict__ W_lam,
                                                  const float* __restrict__ b_lam,
                                                  float* __restrict__ lam) {
  __shared__ float xr[2048];
  __shared__ float part[16][17];
  const int l = blockIdx.x;
  const int tid = threadIdx.x;
#pragma unroll
  for (int i = 0; i < 2; ++i) {
    const int e4 = tid + 256 * i;
    *(float4*)&xr[e4 << 2] = *(const float4*)&x[(size_t)l * 2048 + (e4 << 2)];
  }
  __syncthreads();
  const int h = tid >> 4;
  const int seg = tid & 15;
  float s = 0.f;
  for (int k = seg * 128; k < seg * 128 + 128; ++k)
    s += xr[k] * W_lam[k * 16 + h];
  part[h][seg] = s;
  __syncthreads();
  if (tid < 16) {
    float t = b_lam[tid];
#pragma unroll
    for (int i = 0; i < 16; ++i) t += part[tid][i];
    lam[l * 16 + tid] = 1.0f / (1.0f + expf(-t));
  }
}

// ---------------------------------------------------------------------------
// MFMA flash attention, transposed-score softmax, 32 q-rows per wave.
//  Qb: (2048, 4096) roped bf16 (32 q-heads).  Kb: (2048, 2048) roped bf16.
//  Vt: (2048 dims, 2048 l) bf16.  O: (32, 2048, 128) bf16.
//  Block: 4 waves x 32 q-rows = 128 q-rows; K-tile 64.
//  S^T = K·Q^T: lane owns q-row (s*16+l16), keys t*16+quad*4+r in regs.
//  Each Ks/Vs ds_read feeds 2 MFMAs (s=0,1) — fragment amortization.
// ---------------------------------------------------------------------------
#define ATQ 128
__global__ __launch_bounds__(256, 2) void attn_mfma_kernel(const __bf16* __restrict__ Qb,
                                                           const __bf16* __restrict__ Kb,
                                                           const __bf16* __restrict__ Vt,
                                                           __bf16* __restrict__ O) {
  __shared__ __align__(16) __bf16 Ks[64][136];   // (key, dim) padded
  __shared__ __align__(16) __bf16 Vs[128][72];   // (dim, key) padded
  __shared__ __align__(16) __bf16 Ps[4][32][72]; // per-wave P (qrow, key)
  const int h32 = blockIdx.y;
  const int qt = 15 - (int)blockIdx.x;  // heavy tiles first
  const int q0 = qt * ATQ;
  const int tid = threadIdx.x;
  const int w = tid >> 6;
  const int lane = tid & 63;
  const int quad = lane >> 4;
  const int l16 = lane & 15;
  const int qoff = h32 * 128;
  const int kvoff = (h32 >> 1) * 128;
  const float scale = 0.08838834764831845f;  // 1/sqrt(128)
  const int qrow_base = q0 + w * 32;

  // Q fragments: B-operand for S^T, 2 q-subtiles x 4 k-steps
  bf16x8 aq[2][4];
#pragma unroll
  for (int s = 0; s < 2; ++s) {
    const size_t qbase = (size_t)(qrow_base + s * 16 + l16) * 4096 + qoff + quad * 8;
#pragma unroll
    for (int ks = 0; ks < 4; ++ks)
      aq[s][ks] = *(const bf16x8*)&Qb[qbase + ks * 32];
  }

  f32x4 o[2][8];
#pragma unroll
  for (int s = 0; s < 2; ++s)
#pragma unroll
    for (int i = 0; i < 8; ++i) o[s][i] = (f32x4){0.f, 0.f, 0.f, 0.f};
  float m[2] = {-1e30f, -1e30f}, lsum[2] = {0.f, 0.f};

  const int ktmax = 2 * qt + 1;
  for (int kt = 0; kt <= ktmax; ++kt) {
    const int k0 = kt * 64;
    __syncthreads();  // prev iter's MFMA reads of Ks/Vs done
    // ---- stage K (64x128) and V^T (128x64) ----
#pragma unroll
    for (int i = 0; i < 4; ++i) {
      const int f = tid + 256 * i;             // 0..1023
      const int kr = f >> 4, seg = f & 15;
      *(bf16x8*)&Ks[kr][seg * 8] =
          *(const bf16x8*)&Kb[(size_t)(k0 + kr) * 2048 + kvoff + seg * 8];
      const int dr = f >> 3, sg = f & 7;
      *(bf16x8*)&Vs[dr][sg * 8] =
          *(const bf16x8*)&Vt[(size_t)(kvoff + dr) * 2048 + k0 + sg * 8];
    }
    __syncthreads();
    // ---- S^T = K Q^T : 4 key m-tiles x 4 k-steps x 2 q-subtiles ----
    f32x4 st[2][4];
#pragma unroll
    for (int s = 0; s < 2; ++s)
#pragma unroll
      for (int t = 0; t < 4; ++t) st[s][t] = (f32x4){0.f, 0.f, 0.f, 0.f};
#pragma unroll
    for (int ks = 0; ks < 4; ++ks) {
#pragma unroll
      for (int t = 0; t < 4; ++t) {
        bf16x8 ak = *(bf16x8*)&Ks[t * 16 + l16][ks * 32 + quad * 8];
        st[0][t] = __builtin_amdgcn_mfma_f32_16x16x32_bf16(ak, aq[0][ks], st[0][t], 0, 0, 0);
        st[1][t] = __builtin_amdgcn_mfma_f32_16x16x32_bf16(ak, aq[1][ks], st[1][t], 0, 0, 0);
      }
    }
    // ---- online softmax per q-subtile (lane owns q-row s*16+l16) ----
    const bool masked = (kt >= 2 * qt);
#pragma unroll
    for (int s = 0; s < 2; ++s) {
      const int q = qrow_base + s * 16 + l16;
      float rm = -1e30f;
      if (!masked) {
#pragma unroll
        for (int t = 0; t < 4; ++t)
#pragma unroll
          for (int r = 0; r < 4; ++r) {
            st[s][t][r] *= scale;
            rm = fmaxf(rm, st[s][t][r]);
          }
      } else {
#pragma unroll
        for (int t = 0; t < 4; ++t)
#pragma unroll
          for (int r = 0; r < 4; ++r) {
            const int key = k0 + t * 16 + quad * 4 + r;
            st[s][t][r] = (key <= q) ? st[s][t][r] * scale : -1e30f;
            rm = fmaxf(rm, st[s][t][r]);
          }
      }
      rm = fmaxf(rm, __shfl_xor(rm, 16, 64));
      rm = fmaxf(rm, __shfl_xor(rm, 32, 64));
      const float mn = fmaxf(m[s], rm);
      const float alpha = __expf(m[s] - mn);
      float rs = 0.f;
#pragma unroll
      for (int t = 0; t < 4; ++t)
#pragma unroll
        for (int r = 0; r < 4; ++r) {
          st[s][t][r] = __expf(st[s][t][r] - mn);
          rs += st[s][t][r];
        }
      rs += __shfl_xor(rs, 16, 64);
      rs += __shfl_xor(rs, 32, 64);
      m[s] = mn;
      lsum[s] = lsum[s] * alpha + rs;
      // write P (packed b64)
#pragma unroll
      for (int t = 0; t < 4; ++t) {
        bf16x4 pk = {(__bf16)st[s][t][0], (__bf16)st[s][t][1],
                     (__bf16)st[s][t][2], (__bf16)st[s][t][3]};
        *(bf16x4*)&Ps[w][s * 16 + l16][t * 16 + quad * 4] = pk;
      }
      // rescale O
#pragma unroll
      for (int r = 0; r < 4; ++r) {
        const float ar = __shfl(alpha, quad * 4 + r, 64);
#pragma unroll
        for (int nt = 0; nt < 8; ++nt) o[s][nt][r] *= ar;
      }
    }
    // ---- O += P V : per-wave P (no barrier), each bv feeds 2 MFMAs ----
#pragma unroll
    for (int ks = 0; ks < 2; ++ks) {
      bf16x8 pa0 = *(bf16x8*)&Ps[w][l16][ks * 32 + quad * 8];
      bf16x8 pa1 = *(bf16x8*)&Ps[w][16 + l16][ks * 32 + quad * 8];
#pragma unroll
      for (int nt = 0; nt < 8; ++nt) {
        bf16x8 bv = *(bf16x8*)&Vs[nt * 16 + l16][ks * 32 + quad * 8];
        o[0][nt] = __builtin_amdgcn_mfma_f32_16x16x32_bf16(pa0, bv, o[0][nt], 0, 0, 0);
        o[1][nt] = __builtin_amdgcn_mfma_f32_16x16x32_bf16(pa1, bv, o[1][nt], 0, 0, 0);
      }
    }
  }
  // ---- epilogue: rows = s*16+quad*4+r, cols = nt*16+l16 ----
#pragma unroll
  for (int s = 0; s < 2; ++s) {
    const float linv = 1.0f / lsum[s];
#pragma unroll
    for (int r = 0; r < 4; ++r) {
      const float inv = __shfl(linv, quad * 4 + r, 64);
      const int row = qrow_base + s * 16 + quad * 4 + r;
      __bf16* dst = O + ((size_t)h32 * 2048 + row) * 128;
#pragma unroll
      for (int nt = 0; nt < 8; ++nt)
        dst[nt * 16 + l16] = (__bf16)(o[s][nt][r] * inv);
    }
  }
}

// y[l, h*128+d] = attn[2h, l, d] - lam[l,h] * attn[2h+1, l, d]   (bf16 in/out)
__global__ __launch_bounds__(256) void combine_kernel(const __bf16* __restrict__ attn,
                                                      const float* __restrict__ lam,
                                                      __bf16* __restrict__ y) {
  const int l = blockIdx.x;
  const int tid = threadIdx.x;
  const int h = tid >> 4;
  const int d = (tid & 15) * 8;
  const float lm = lam[l * 16 + h];
  bf16x8 a1 = *(const bf16x8*)&attn[((size_t)(2 * h) * 2048 + l) * 128 + d];
  bf16x8 a2 = *(const bf16x8*)&attn[((size_t)(2 * h + 1) * 2048 + l) * 128 + d];
  bf16x8 o;
#pragma unroll
  for (int i = 0; i < 8; ++i) o[i] = (__bf16)((float)a1[i] - lm * (float)a2[i]);
  *(bf16x8*)&y[(size_t)l * 2048 + h * 128 + d] = o;
}

extern "C" void kernel_launch(void* const* d_in, const int* in_sizes, int n_in,
                              void* d_out, int out_size, void* d_ws, size_t ws_size,
                              hipStream_t stream) {
  const float* x     = (const float*)d_in[0];
  const float* W_DKV = (const float*)d_in[1];
  const float* W_UK  = (const float*)d_in[2];
  const float* W_UV  = (const float*)d_in[3];
  const float* W_DQ  = (const float*)d_in[4];
  const float* W_UQ  = (const float*)d_in[5];
  const float* W_lam = (const float*)d_in[6];
  const float* b_lam = (const float*)d_in[7];
  const float* W_out = (const float*)d_in[8];
  float* out = (float*)d_out;

  char* ws = (char*)d_ws;
  #define MB(n) ((size_t)(n) << 20)
  __bf16* x_bf   = (__bf16*)(ws + MB(0));    //  8 MB (2048x2048)
  __bf16* Wt_out = (__bf16*)(ws + MB(0));    //  8 MB alias: x_bf dead after down-proj
  __bf16* Wt_DKV = (__bf16*)(ws + MB(8));    //  2 MB (512x2048)
  __bf16* Wt_DQ  = (__bf16*)(ws + MB(10));   //  4 MB (1024x2048)
  __bf16* c_kv   = (__bf16*)(ws + MB(14));   //  2 MB (2048x512)
  __bf16* c_q    = (__bf16*)(ws + MB(16));   //  4 MB (2048x1024)
  __bf16* Wt_UK  = (__bf16*)(ws + MB(20));   //  2 MB (2048x512)
  __bf16* Wt_UV  = (__bf16*)(ws + MB(22));   //  2 MB (2048x512)
  __bf16* Wt_UQ  = (__bf16*)(ws + MB(24));   //  8 MB (4096x1024)
  __bf16* k_bf   = (__bf16*)(ws + MB(32));   //  8 MB (2048x2048)
  __bf16* v_bf   = (__bf16*)(ws + MB(40));   //  8 MB (2048x2048)
  __bf16* y_bf   = (__bf16*)(ws + MB(40));   //  8 MB alias: v_bf dead after v_t
  __bf16* q_bf   = (__bf16*)(ws + MB(48));   // 16 MB (2048x4096)
  __bf16* v_t    = (__bf16*)(ws + MB(64));   //  8 MB (2048x2048)
  __bf16* attn   = (__bf16*)(ws + MB(72));   // 16 MB (32x2048x128) bf16
  float*  lam    = (float*)(ws + MB(88));    // 128 KB
  float*  cosT   = (float*)(ws + MB(89));    //  1 MB
  float*  sinT   = (float*)(ws + MB(90));    //  1 MB  (total 91 MB)

  rope_table_kernel<<<2048, 128, 0, stream>>>(cosT, sinT);
  cast_kernel<<<4096, 256, 0, stream>>>(x, x_bf);
  castT_kernel<<<dim3(64, 16), 256, 0, stream>>>(W_DKV, Wt_DKV, 2048, 512);
  castT_kernel<<<dim3(64, 32), 256, 0, stream>>>(W_DQ,  Wt_DQ,  2048, 1024);
  castT_kernel<<<dim3(16, 64), 256, 0, stream>>>(W_UK,  Wt_UK,  512,  2048);
  castT_kernel<<<dim3(16, 64), 256, 0, stream>>>(W_UV,  Wt_UV,  512,  2048);
  castT_kernel<<<dim3(32, 128), 256, 0, stream>>>(W_UQ, Wt_UQ,  1024, 4096);
  // fused down-projections: DKV (4 x-tiles) + DQ (8 x-tiles)
  gemm_fused3<<<dim3(12, 16), 256, 0, stream>>>(
      x_bf, Wt_DKV, c_kv, 512, 2048, 4,
      x_bf, Wt_DQ,  c_q, 1024, 2048, 8,
      x_bf, Wt_DQ,  c_q, 1024, 2048);
  castT_kernel<<<dim3(64, 64), 256, 0, stream>>>(W_out, Wt_out, 2048, 2048);
  // fused up-projections: UK (16) + UV (16) + UQ (32)
  gemm_fused3<<<dim3(64, 16), 256, 0, stream>>>(
      c_kv, Wt_UK, k_bf, 2048, 512, 16,
      c_kv, Wt_UV, v_bf, 2048, 512, 16,
      c_q,  Wt_UQ, q_bf, 4096, 1024);
  rope_bf16_kernel<<<2048, 256, 0, stream>>>(k_bf, cosT, sinT, 2048);
  rope_bf16_kernel<<<2048, 256, 0, stream>>>(q_bf, cosT, sinT, 4096);
  transpose_bf16_kernel<<<dim3(64, 64), 256, 0, stream>>>(v_bf, v_t);
  lam_kernel<<<2048, 256, 0, stream>>>(x, W_lam, b_lam, lam);
  attn_mfma_kernel<<<dim3(2048 / ATQ, 32), 256, 0, stream>>>(q_bf, k_bf, v_t, attn);
  combine_kernel<<<2048, 256, 0, stream>>>(attn, lam, y_bf);
  gemm_mfma<false><<<dim3(16, 16), 256, 0, stream>>>(y_bf, Wt_out, out, 2048, 2048, 2048);
}

// Round 6
// 411.227 us; speedup vs baseline: 9.0392x; 1.2408x over previous
//
#include <hip/hip_runtime.h>
#include <cstdint>
#include <cstddef>

typedef __bf16 bf16x8 __attribute__((ext_vector_type(8)));
typedef __bf16 bf16x4 __attribute__((ext_vector_type(4)));
typedef float f32x4 __attribute__((ext_vector_type(4)));

// ---------------------------------------------------------------------------
// Problem constants (B=1): D=2048, NH=16, DH=128, DC=512, DCQ=1024, L=2048
// ---------------------------------------------------------------------------

// ---------------------------------------------------------------------------
// MFMA GEMM core: C(M,N) = A(M,K) @ Bt(N,K)^T.  A,Bt row-major bf16.
// 128x128 tile, BK=32, 4 waves, each wave 64x64 (4x4 of 16x16x32 MFMA).
// ---------------------------------------------------------------------------
template <bool BF16OUT>
__device__ __forceinline__ void gemm_body(const __bf16* __restrict__ A,
                                          const __bf16* __restrict__ Bt,
                                          void* __restrict__ Cv,
                                          int N, int K, int bm, int bn,
                                          __bf16* As, __bf16* Bs) {
  const int tid = threadIdx.x;
  const int w = tid >> 6;
  const int lane = tid & 63;
  const int quad = lane >> 4;
  const int l16 = lane & 15;
  const int wm = (w & 1) * 64;
  const int wn = (w >> 1) * 64;
  const int srow = lane >> 2;
  const int sseg = (lane & 3) * 8;

  f32x4 acc[4][4];
#pragma unroll
  for (int i = 0; i < 4; ++i)
#pragma unroll
    for (int j = 0; j < 4; ++j) acc[i][j] = (f32x4){0.f, 0.f, 0.f, 0.f};

  for (int k0 = 0; k0 < K; k0 += 32) {
    __syncthreads();
#pragma unroll
    for (int g = 0; g < 2; ++g) {
      const int grp = w + g * 4;
      const __bf16* ga = A + (size_t)(bm + grp * 16 + srow) * K + k0 + sseg;
      const __bf16* gb = Bt + (size_t)(bn + grp * 16 + srow) * K + k0 + sseg;
      __builtin_amdgcn_global_load_lds(
          (const __attribute__((address_space(1))) void*)ga,
          (__attribute__((address_space(3))) void*)&As[grp * 512], 16, 0, 0);
      __builtin_amdgcn_global_load_lds(
          (const __attribute__((address_space(1))) void*)gb,
          (__attribute__((address_space(3))) void*)&Bs[grp * 512], 16, 0, 0);
    }
    __syncthreads();
    bf16x8 af[4], bfr[4];
#pragma unroll
    for (int i = 0; i < 4; ++i) {
      af[i] = *(const bf16x8*)&As[(wm + i * 16 + l16) * 32 + quad * 8];
      bfr[i] = *(const bf16x8*)&Bs[(wn + i * 16 + l16) * 32 + quad * 8];
    }
#pragma unroll
    for (int i = 0; i < 4; ++i)
#pragma unroll
      for (int j = 0; j < 4; ++j)
        acc[i][j] = __builtin_amdgcn_mfma_f32_16x16x32_bf16(af[i], bfr[j],
                                                            acc[i][j], 0, 0, 0);
  }
#pragma unroll
  for (int i = 0; i < 4; ++i)
#pragma unroll
    for (int j = 0; j < 4; ++j)
#pragma unroll
      for (int r = 0; r < 4; ++r) {
        const int row = bm + wm + i * 16 + quad * 4 + r;
        const int col = bn + wn + j * 16 + l16;
        if constexpr (BF16OUT)
          ((__bf16*)Cv)[(size_t)row * N + col] = (__bf16)acc[i][j][r];
        else
          ((float*)Cv)[(size_t)row * N + col] = acc[i][j][r];
      }
}

template <bool BF16OUT>
__global__ __launch_bounds__(256) void gemm_mfma(const __bf16* __restrict__ A,
                                                 const __bf16* __restrict__ Bt,
                                                 void* __restrict__ Cv,
                                                 int M, int N, int K) {
  __shared__ __bf16 As[128 * 32];
  __shared__ __bf16 Bs[128 * 32];
  gemm_body<BF16OUT>(A, Bt, Cv, N, K, blockIdx.y * 128, blockIdx.x * 128, As, Bs);
}

// Up to 3 independent GEMMs fused by blockIdx.x ranges [0,nx0), [nx0,nx0+nx1), rest.
__global__ __launch_bounds__(256) void gemm_fused3(
    const __bf16* A0, const __bf16* B0, __bf16* C0, int N0, int K0, int nx0,
    const __bf16* A1, const __bf16* B1, __bf16* C1, int N1, int K1, int nx1,
    const __bf16* A2, const __bf16* B2, __bf16* C2, int N2, int K2) {
  __shared__ __bf16 As[128 * 32];
  __shared__ __bf16 Bs[128 * 32];
  const int bx = blockIdx.x;
  const __bf16 *A, *Bt;
  __bf16* C;
  int N, K, bxl;
  if (bx < nx0)            { A = A0; Bt = B0; C = C0; N = N0; K = K0; bxl = bx; }
  else if (bx < nx0 + nx1) { A = A1; Bt = B1; C = C1; N = N1; K = K1; bxl = bx - nx0; }
  else                     { A = A2; Bt = B2; C = C2; N = N2; K = K2; bxl = bx - nx0 - nx1; }
  gemm_body<true>(A, Bt, (void*)C, N, K, blockIdx.y * 128, bxl * 128, As, Bs);
}

// fp32 (K,N) -> bf16 (N,K) transpose-cast.  Grid (K/32, N/32), 256 thr.
__global__ __launch_bounds__(256) void castT_kernel(const float* __restrict__ src,
                                                    __bf16* __restrict__ dst,
                                                    int K, int N) {
  __shared__ float T[32][36];
  const int k0 = blockIdx.x * 32;
  const int n0 = blockIdx.y * 32;
  const int r = threadIdx.x >> 3;
  const int c = (threadIdx.x & 7) * 4;
  *(float4*)&T[r][c] = *(const float4*)&src[(size_t)(k0 + r) * N + n0 + c];
  __syncthreads();
  bf16x4 o = {(__bf16)T[c + 0][r], (__bf16)T[c + 1][r],
              (__bf16)T[c + 2][r], (__bf16)T[c + 3][r]};
  *(bf16x4*)&dst[(size_t)(n0 + r) * K + k0 + c] = o;
}

// elementwise fp32 -> bf16 (n multiple of 1024)
__global__ __launch_bounds__(256) void cast_kernel(const float* __restrict__ src,
                                                   __bf16* __restrict__ dst) {
  const int i = blockIdx.x * 256 + threadIdx.x;
  float4 v = *(const float4*)&src[i * 4];
  bf16x4 o = {(__bf16)v.x, (__bf16)v.y, (__bf16)v.z, (__bf16)v.w};
  *(bf16x4*)&dst[i * 4] = o;
}

// cos/sin tables: (L, 128).  inv_freq[j] = 10000^(-j/64), j = d & 63.
__global__ void rope_table_kernel(float* __restrict__ cosT,
                                  float* __restrict__ sinT) {
  const int l = blockIdx.x;
  const int d = threadIdx.x;
  const int j = d & 63;
  const float inv = powf(10000.0f, -(float)j * (1.0f / 64.0f));
  const float ang = (float)l * inv;
  cosT[l * 128 + d] = cosf(ang);
  sinT[l * 128 + d] = sinf(ang);
}

// In-place RoPE on a (2048, W) row-major bf16 tensor; heads of 128 along W.
__global__ __launch_bounds__(256) void rope_bf16_kernel(__bf16* __restrict__ T,
                                                        const float* __restrict__ cosT,
                                                        const float* __restrict__ sinT,
                                                        int W) {
  __shared__ float row[4096];
  const int l = blockIdx.x;
  const int tid = threadIdx.x;
  __bf16* rp = T + (size_t)l * W;
  for (int e4 = tid; e4 * 4 < W; e4 += 256) {
    bf16x4 v = *(const bf16x4*)&rp[e4 * 4];
#pragma unroll
    for (int i = 0; i < 4; ++i) row[e4 * 4 + i] = (float)v[i];
  }
  __syncthreads();
  for (int e = tid; e < W; e += 256) {
    const int d = e & 127;
    const float c = cosT[l * 128 + d];
    const float s = sinT[l * 128 + d];
    const float t = row[e];
    const int base = e & ~127;
    const float rot = (d < 64) ? -row[base + d + 64] : row[base + d - 64];
    rp[e] = (__bf16)(t * c + rot * s);
  }
}

// (2048 l, 2048 dims) bf16  ->  (2048 dims, 2048 l) bf16
__global__ __launch_bounds__(256) void transpose_bf16_kernel(const __bf16* __restrict__ src,
                                                             __bf16* __restrict__ dst) {
  __shared__ __align__(16) __bf16 Ts[32][40];
  const int l0 = blockIdx.x * 32;
  const int d0 = blockIdx.y * 32;
  const int r = threadIdx.x >> 3;
  const int c = (threadIdx.x & 7) * 4;
  *(bf16x4*)&Ts[r][c] = *(const bf16x4*)&src[(size_t)(l0 + r) * 2048 + d0 + c];
  __syncthreads();
  bf16x4 o = {Ts[c + 0][r], Ts[c + 1][r], Ts[c + 2][r], Ts[c + 3][r]};
  *(bf16x4*)&dst[(size_t)(d0 + r) * 2048 + l0 + c] = o;
}

// W_lam (2048,16) f32 -> WlT (16,2048) bf16
__global__ __launch_bounds__(256) void lamT_kernel(const float* __restrict__ W_lam,
                                                   __bf16* __restrict__ WlT) {
  const int i = blockIdx.x * 256 + threadIdx.x;  // 0..32767
  const int k = i >> 4, n = i & 15;
  WlT[(size_t)n * 2048 + k] = (__bf16)W_lam[i];
}

// lam(l,h) = sigmoid(x_bf[l,:] . W_lam[:,h] + b_lam[h]) via MFMA (N=16).
// Grid 32 x 256; wave handles m-tile (blockIdx*4+w)*16 rows. No LDS.
__global__ __launch_bounds__(256) void lam_mfma_kernel(const __bf16* __restrict__ x_bf,
                                                       const __bf16* __restrict__ WlT,
                                                       const float* __restrict__ b_lam,
                                                       float* __restrict__ lam) {
  const int tid = threadIdx.x;
  const int w = tid >> 6, lane = tid & 63, quad = lane >> 4, l16 = lane & 15;
  const int m0 = (blockIdx.x * 4 + w) * 16;
  const __bf16* xrow = x_bf + (size_t)(m0 + l16) * 2048 + quad * 8;
  const __bf16* wrow = WlT + (size_t)l16 * 2048 + quad * 8;
  f32x4 acc[4];
#pragma unroll
  for (int u = 0; u < 4; ++u) acc[u] = (f32x4){0.f, 0.f, 0.f, 0.f};
  for (int k0 = 0; k0 < 2048; k0 += 128) {
#pragma unroll
    for (int u = 0; u < 4; ++u) {
      bf16x8 a = *(const bf16x8*)&xrow[k0 + u * 32];
      bf16x8 b = *(const bf16x8*)&wrow[k0 + u * 32];
      acc[u] = __builtin_amdgcn_mfma_f32_16x16x32_bf16(a, b, acc[u], 0, 0, 0);
    }
  }
  const float bl = b_lam[l16];
#pragma unroll
  for (int r = 0; r < 4; ++r) {
    const float v = acc[0][r] + acc[1][r] + acc[2][r] + acc[3][r] + bl;
    lam[(size_t)(m0 + quad * 4 + r) * 16 + l16] = 1.0f / (1.0f + __expf(-v));
  }
}

// ---------------------------------------------------------------------------
// MFMA flash attention, transposed-score softmax, 32 q-rows per wave.
// ---------------------------------------------------------------------------
#define ATQ 128
__global__ __launch_bounds__(256, 2) void attn_mfma_kernel(const __bf16* __restrict__ Qb,
                                                           const __bf16* __restrict__ Kb,
                                                           const __bf16* __restrict__ Vt,
                                                           __bf16* __restrict__ O) {
  __shared__ __align__(16) __bf16 Ks[64][136];   // (key, dim) padded
  __shared__ __align__(16) __bf16 Vs[128][72];   // (dim, key) padded
  __shared__ __align__(16) __bf16 Ps[4][32][72]; // per-wave P (qrow, key)
  const int h32 = blockIdx.y;
  const int qt = 15 - (int)blockIdx.x;  // heavy tiles first
  const int q0 = qt * ATQ;
  const int tid = threadIdx.x;
  const int w = tid >> 6;
  const int lane = tid & 63;
  const int quad = lane >> 4;
  const int l16 = lane & 15;
  const int qoff = h32 * 128;
  const int kvoff = (h32 >> 1) * 128;
  const float scale = 0.08838834764831845f;  // 1/sqrt(128)
  const int qrow_base = q0 + w * 32;

  bf16x8 aq[2][4];
#pragma unroll
  for (int s = 0; s < 2; ++s) {
    const size_t qbase = (size_t)(qrow_base + s * 16 + l16) * 4096 + qoff + quad * 8;
#pragma unroll
    for (int ks = 0; ks < 4; ++ks)
      aq[s][ks] = *(const bf16x8*)&Qb[qbase + ks * 32];
  }

  f32x4 o[2][8];
#pragma unroll
  for (int s = 0; s < 2; ++s)
#pragma unroll
    for (int i = 0; i < 8; ++i) o[s][i] = (f32x4){0.f, 0.f, 0.f, 0.f};
  float m[2] = {-1e30f, -1e30f}, lsum[2] = {0.f, 0.f};

  const int ktmax = 2 * qt + 1;
  for (int kt = 0; kt <= ktmax; ++kt) {
    const int k0 = kt * 64;
    __syncthreads();
#pragma unroll
    for (int i = 0; i < 4; ++i) {
      const int f = tid + 256 * i;
      const int kr = f >> 4, seg = f & 15;
      *(bf16x8*)&Ks[kr][seg * 8] =
          *(const bf16x8*)&Kb[(size_t)(k0 + kr) * 2048 + kvoff + seg * 8];
      const int dr = f >> 3, sg = f & 7;
      *(bf16x8*)&Vs[dr][sg * 8] =
          *(const bf16x8*)&Vt[(size_t)(kvoff + dr) * 2048 + k0 + sg * 8];
    }
    __syncthreads();
    f32x4 st[2][4];
#pragma unroll
    for (int s = 0; s < 2; ++s)
#pragma unroll
      for (int t = 0; t < 4; ++t) st[s][t] = (f32x4){0.f, 0.f, 0.f, 0.f};
#pragma unroll
    for (int ks = 0; ks < 4; ++ks) {
#pragma unroll
      for (int t = 0; t < 4; ++t) {
        bf16x8 ak = *(bf16x8*)&Ks[t * 16 + l16][ks * 32 + quad * 8];
        st[0][t] = __builtin_amdgcn_mfma_f32_16x16x32_bf16(ak, aq[0][ks], st[0][t], 0, 0, 0);
        st[1][t] = __builtin_amdgcn_mfma_f32_16x16x32_bf16(ak, aq[1][ks], st[1][t], 0, 0, 0);
      }
    }
    const bool masked = (kt >= 2 * qt);
#pragma unroll
    for (int s = 0; s < 2; ++s) {
      const int q = qrow_base + s * 16 + l16;
      float rm = -1e30f;
      if (!masked) {
#pragma unroll
        for (int t = 0; t < 4; ++t)
#pragma unroll
          for (int r = 0; r < 4; ++r) {
            st[s][t][r] *= scale;
            rm = fmaxf(rm, st[s][t][r]);
          }
      } else {
#pragma unroll
        for (int t = 0; t < 4; ++t)
#pragma unroll
          for (int r = 0; r < 4; ++r) {
            const int key = k0 + t * 16 + quad * 4 + r;
            st[s][t][r] = (key <= q) ? st[s][t][r] * scale : -1e30f;
            rm = fmaxf(rm, st[s][t][r]);
          }
      }
      rm = fmaxf(rm, __shfl_xor(rm, 16, 64));
      rm = fmaxf(rm, __shfl_xor(rm, 32, 64));
      const float mn = fmaxf(m[s], rm);
      const float alpha = __expf(m[s] - mn);
      float rs = 0.f;
#pragma unroll
      for (int t = 0; t < 4; ++t)
#pragma unroll
        for (int r = 0; r < 4; ++r) {
          st[s][t][r] = __expf(st[s][t][r] - mn);
          rs += st[s][t][r];
        }
      rs += __shfl_xor(rs, 16, 64);
      rs += __shfl_xor(rs, 32, 64);
      m[s] = mn;
      lsum[s] = lsum[s] * alpha + rs;
#pragma unroll
      for (int t = 0; t < 4; ++t) {
        bf16x4 pk = {(__bf16)st[s][t][0], (__bf16)st[s][t][1],
                     (__bf16)st[s][t][2], (__bf16)st[s][t][3]};
        *(bf16x4*)&Ps[w][s * 16 + l16][t * 16 + quad * 4] = pk;
      }
#pragma unroll
      for (int r = 0; r < 4; ++r) {
        const float ar = __shfl(alpha, quad * 4 + r, 64);
#pragma unroll
        for (int nt = 0; nt < 8; ++nt) o[s][nt][r] *= ar;
      }
    }
#pragma unroll
    for (int ks = 0; ks < 2; ++ks) {
      bf16x8 pa0 = *(bf16x8*)&Ps[w][l16][ks * 32 + quad * 8];
      bf16x8 pa1 = *(bf16x8*)&Ps[w][16 + l16][ks * 32 + quad * 8];
#pragma unroll
      for (int nt = 0; nt < 8; ++nt) {
        bf16x8 bv = *(bf16x8*)&Vs[nt * 16 + l16][ks * 32 + quad * 8];
        o[0][nt] = __builtin_amdgcn_mfma_f32_16x16x32_bf16(pa0, bv, o[0][nt], 0, 0, 0);
        o[1][nt] = __builtin_amdgcn_mfma_f32_16x16x32_bf16(pa1, bv, o[1][nt], 0, 0, 0);
      }
    }
  }
#pragma unroll
  for (int s = 0; s < 2; ++s) {
    const float linv = 1.0f / lsum[s];
#pragma unroll
    for (int r = 0; r < 4; ++r) {
      const float inv = __shfl(linv, quad * 4 + r, 64);
      const int row = qrow_base + s * 16 + quad * 4 + r;
      __bf16* dst = O + ((size_t)h32 * 2048 + row) * 128;
#pragma unroll
      for (int nt = 0; nt < 8; ++nt)
        dst[nt * 16 + l16] = (__bf16)(o[s][nt][r] * inv);
    }
  }
}

// y[l, h*128+d] = attn[2h, l, d] - lam[l,h] * attn[2h+1, l, d]   (bf16 in/out)
__global__ __launch_bounds__(256) void combine_kernel(const __bf16* __restrict__ attn,
                                                      const float* __restrict__ lam,
                                                      __bf16* __restrict__ y) {
  const int l = blockIdx.x;
  const int tid = threadIdx.x;
  const int h = tid >> 4;
  const int d = (tid & 15) * 8;
  const float lm = lam[l * 16 + h];
  bf16x8 a1 = *(const bf16x8*)&attn[((size_t)(2 * h) * 2048 + l) * 128 + d];
  bf16x8 a2 = *(const bf16x8*)&attn[((size_t)(2 * h + 1) * 2048 + l) * 128 + d];
  bf16x8 o;
#pragma unroll
  for (int i = 0; i < 8; ++i) o[i] = (__bf16)((float)a1[i] - lm * (float)a2[i]);
  *(bf16x8*)&y[(size_t)l * 2048 + h * 128 + d] = o;
}

extern "C" void kernel_launch(void* const* d_in, const int* in_sizes, int n_in,
                              void* d_out, int out_size, void* d_ws, size_t ws_size,
                              hipStream_t stream) {
  const float* x     = (const float*)d_in[0];
  const float* W_DKV = (const float*)d_in[1];
  const float* W_UK  = (const float*)d_in[2];
  const float* W_UV  = (const float*)d_in[3];
  const float* W_DQ  = (const float*)d_in[4];
  const float* W_UQ  = (const float*)d_in[5];
  const float* W_lam = (const float*)d_in[6];
  const float* b_lam = (const float*)d_in[7];
  const float* W_out = (const float*)d_in[8];
  float* out = (float*)d_out;

  char* ws = (char*)d_ws;
  #define MB(n) ((size_t)(n) << 20)
  __bf16* x_bf   = (__bf16*)(ws + MB(0));    //  8 MB (2048x2048)
  __bf16* Wt_DKV = (__bf16*)(ws + MB(8));    //  2 MB (512x2048)
  __bf16* Wt_DQ  = (__bf16*)(ws + MB(10));   //  4 MB (1024x2048)
  __bf16* c_kv   = (__bf16*)(ws + MB(14));   //  2 MB (2048x512)
  __bf16* c_q    = (__bf16*)(ws + MB(16));   //  4 MB (2048x1024)
  __bf16* Wt_UK  = (__bf16*)(ws + MB(20));   //  2 MB (2048x512)
  __bf16* Wt_UV  = (__bf16*)(ws + MB(22));   //  2 MB (2048x512)
  __bf16* Wt_UQ  = (__bf16*)(ws + MB(24));   //  8 MB (4096x1024)
  __bf16* k_bf   = (__bf16*)(ws + MB(32));   //  8 MB (2048x2048)
  __bf16* v_bf   = (__bf16*)(ws + MB(40));   //  8 MB (2048x2048)
  __bf16* y_bf   = (__bf16*)(ws + MB(40));   //  8 MB alias: v_bf dead after v_t
  __bf16* q_bf   = (__bf16*)(ws + MB(48));   // 16 MB (2048x4096)
  __bf16* v_t    = (__bf16*)(ws + MB(64));   //  8 MB (2048x2048)
  __bf16* attn   = (__bf16*)(ws + MB(72));   // 16 MB (32x2048x128) bf16
  float*  lam    = (float*)(ws + MB(88));    // 128 KB
  float*  cosT   = (float*)(ws + MB(89));    //  1 MB
  float*  sinT   = (float*)(ws + MB(90));    //  1 MB
  __bf16* WlT    = (__bf16*)(ws + MB(91));   // 64 KB (16x2048)
  __bf16* Wt_out = (__bf16*)(ws + MB(92));   //  8 MB (2048x2048)  (total 100 MB)

  rope_table_kernel<<<2048, 128, 0, stream>>>(cosT, sinT);
  cast_kernel<<<4096, 256, 0, stream>>>(x, x_bf);
  castT_kernel<<<dim3(64, 16), 256, 0, stream>>>(W_DKV, Wt_DKV, 2048, 512);
  castT_kernel<<<dim3(64, 32), 256, 0, stream>>>(W_DQ,  Wt_DQ,  2048, 1024);
  castT_kernel<<<dim3(16, 64), 256, 0, stream>>>(W_UK,  Wt_UK,  512,  2048);
  castT_kernel<<<dim3(16, 64), 256, 0, stream>>>(W_UV,  Wt_UV,  512,  2048);
  castT_kernel<<<dim3(32, 128), 256, 0, stream>>>(W_UQ, Wt_UQ,  1024, 4096);
  lamT_kernel<<<128, 256, 0, stream>>>(W_lam, WlT);
  // fused down-projections: DKV (4 x-tiles) + DQ (8 x-tiles)
  gemm_fused3<<<dim3(12, 16), 256, 0, stream>>>(
      x_bf, Wt_DKV, c_kv, 512, 2048, 4,
      x_bf, Wt_DQ,  c_q, 1024, 2048, 8,
      x_bf, Wt_DQ,  c_q, 1024, 2048);
  // gate (MFMA, N=16) — uses x_bf
  lam_mfma_kernel<<<32, 256, 0, stream>>>(x_bf, WlT, b_lam, lam);
  castT_kernel<<<dim3(64, 64), 256, 0, stream>>>(W_out, Wt_out, 2048, 2048);
  // fused up-projections: UK (16) + UV (16) + UQ (32)
  gemm_fused3<<<dim3(64, 16), 256, 0, stream>>>(
      c_kv, Wt_UK, k_bf, 2048, 512, 16,
      c_kv, Wt_UV, v_bf, 2048, 512, 16,
      c_q,  Wt_UQ, q_bf, 4096, 1024);
  rope_bf16_kernel<<<2048, 256, 0, stream>>>(k_bf, cosT, sinT, 2048);
  rope_bf16_kernel<<<2048, 256, 0, stream>>>(q_bf, cosT, sinT, 4096);
  transpose_bf16_kernel<<<dim3(64, 64), 256, 0, stream>>>(v_bf, v_t);
  attn_mfma_kernel<<<dim3(2048 / ATQ, 32), 256, 0, stream>>>(q_bf, k_bf, v_t, attn);
  combine_kernel<<<2048, 256, 0, stream>>>(attn, lam, y_bf);
  gemm_mfma<false><<<dim3(16, 16), 256, 0, stream>>>(y_bf, Wt_out, out, 2048, 2048, 2048);
}

// Round 7
// 371.343 us; speedup vs baseline: 10.0100x; 1.1074x over previous
//
#include <hip/hip_runtime.h>
#include <cstdint>
#include <cstddef>

typedef __bf16 bf16x8 __attribute__((ext_vector_type(8)));
typedef __bf16 bf16x4 __attribute__((ext_vector_type(4)));
typedef float f32x4 __attribute__((ext_vector_type(4)));

// ---------------------------------------------------------------------------
// Problem constants (B=1): D=2048, NH=16, DH=128, DC=512, DCQ=1024, L=2048
// ---------------------------------------------------------------------------

// ---------------------------------------------------------------------------
// MFMA GEMM core: C(M,N) = A(M,K) @ Bt(N,K)^T.  A,Bt row-major bf16.
// 128x128 tile, BK=32, 4 waves, each wave 64x64 (4x4 of 16x16x32 MFMA).
// ---------------------------------------------------------------------------
template <bool BF16OUT>
__device__ __forceinline__ void gemm_body(const __bf16* __restrict__ A,
                                          const __bf16* __restrict__ Bt,
                                          void* __restrict__ Cv,
                                          int N, int K, int bm, int bn,
                                          __bf16* As, __bf16* Bs) {
  const int tid = threadIdx.x;
  const int w = tid >> 6;
  const int lane = tid & 63;
  const int quad = lane >> 4;
  const int l16 = lane & 15;
  const int wm = (w & 1) * 64;
  const int wn = (w >> 1) * 64;
  const int srow = lane >> 2;
  const int sseg = (lane & 3) * 8;

  f32x4 acc[4][4];
#pragma unroll
  for (int i = 0; i < 4; ++i)
#pragma unroll
    for (int j = 0; j < 4; ++j) acc[i][j] = (f32x4){0.f, 0.f, 0.f, 0.f};

  for (int k0 = 0; k0 < K; k0 += 32) {
    __syncthreads();
#pragma unroll
    for (int g = 0; g < 2; ++g) {
      const int grp = w + g * 4;
      const __bf16* ga = A + (size_t)(bm + grp * 16 + srow) * K + k0 + sseg;
      const __bf16* gb = Bt + (size_t)(bn + grp * 16 + srow) * K + k0 + sseg;
      __builtin_amdgcn_global_load_lds(
          (const __attribute__((address_space(1))) void*)ga,
          (__attribute__((address_space(3))) void*)&As[grp * 512], 16, 0, 0);
      __builtin_amdgcn_global_load_lds(
          (const __attribute__((address_space(1))) void*)gb,
          (__attribute__((address_space(3))) void*)&Bs[grp * 512], 16, 0, 0);
    }
    __syncthreads();
    bf16x8 af[4], bfr[4];
#pragma unroll
    for (int i = 0; i < 4; ++i) {
      af[i] = *(const bf16x8*)&As[(wm + i * 16 + l16) * 32 + quad * 8];
      bfr[i] = *(const bf16x8*)&Bs[(wn + i * 16 + l16) * 32 + quad * 8];
    }
#pragma unroll
    for (int i = 0; i < 4; ++i)
#pragma unroll
      for (int j = 0; j < 4; ++j)
        acc[i][j] = __builtin_amdgcn_mfma_f32_16x16x32_bf16(af[i], bfr[j],
                                                            acc[i][j], 0, 0, 0);
  }
#pragma unroll
  for (int i = 0; i < 4; ++i)
#pragma unroll
    for (int j = 0; j < 4; ++j)
#pragma unroll
      for (int r = 0; r < 4; ++r) {
        const int row = bm + wm + i * 16 + quad * 4 + r;
        const int col = bn + wn + j * 16 + l16;
        if constexpr (BF16OUT)
          ((__bf16*)Cv)[(size_t)row * N + col] = (__bf16)acc[i][j][r];
        else
          ((float*)Cv)[(size_t)row * N + col] = acc[i][j][r];
      }
}

template <bool BF16OUT>
__global__ __launch_bounds__(256) void gemm_mfma(const __bf16* __restrict__ A,
                                                 const __bf16* __restrict__ Bt,
                                                 void* __restrict__ Cv,
                                                 int M, int N, int K) {
  __shared__ __bf16 As[128 * 32];
  __shared__ __bf16 Bs[128 * 32];
  gemm_body<BF16OUT>(A, Bt, Cv, N, K, blockIdx.y * 128, blockIdx.x * 128, As, Bs);
}

// Up to 3 independent GEMMs fused by blockIdx.x ranges.
__global__ __launch_bounds__(256) void gemm_fused3(
    const __bf16* A0, const __bf16* B0, __bf16* C0, int N0, int K0, int nx0,
    const __bf16* A1, const __bf16* B1, __bf16* C1, int N1, int K1, int nx1,
    const __bf16* A2, const __bf16* B2, __bf16* C2, int N2, int K2) {
  __shared__ __bf16 As[128 * 32];
  __shared__ __bf16 Bs[128 * 32];
  const int bx = blockIdx.x;
  const __bf16 *A, *Bt;
  __bf16* C;
  int N, K, bxl;
  if (bx < nx0)            { A = A0; Bt = B0; C = C0; N = N0; K = K0; bxl = bx; }
  else if (bx < nx0 + nx1) { A = A1; Bt = B1; C = C1; N = N1; K = K1; bxl = bx - nx0; }
  else                     { A = A2; Bt = B2; C = C2; N = N2; K = K2; bxl = bx - nx0 - nx1; }
  gemm_body<true>(A, Bt, (void*)C, N, K, blockIdx.y * 128, bxl * 128, As, Bs);
}

// All six weight transposes fused: fp32 (K,N) -> bf16 (N,K), 32x32 tiles.
__global__ __launch_bounds__(256) void castT_all(
    const float* __restrict__ W_DKV, const float* __restrict__ W_DQ,
    const float* __restrict__ W_UK,  const float* __restrict__ W_UV,
    const float* __restrict__ W_UQ,  const float* __restrict__ W_out,
    __bf16* __restrict__ tDKV, __bf16* __restrict__ tDQ,
    __bf16* __restrict__ tUK,  __bf16* __restrict__ tUV,
    __bf16* __restrict__ tUQ,  __bf16* __restrict__ tOut) {
  int t = blockIdx.x;
  const float* src; __bf16* dst; int K, N, kx, ny;
  if (t < 1024)      {            src = W_DKV; dst = tDKV; K = 2048; N = 512;  kx = t & 63; ny = t >> 6; }
  else if (t < 3072) { t -= 1024; src = W_DQ;  dst = tDQ;  K = 2048; N = 1024; kx = t & 63; ny = t >> 6; }
  else if (t < 4096) { t -= 3072; src = W_UK;  dst = tUK;  K = 512;  N = 2048; kx = t & 15; ny = t >> 4; }
  else if (t < 5120) { t -= 4096; src = W_UV;  dst = tUV;  K = 512;  N = 2048; kx = t & 15; ny = t >> 4; }
  else if (t < 9216) { t -= 5120; src = W_UQ;  dst = tUQ;  K = 1024; N = 4096; kx = t & 31; ny = t >> 5; }
  else               { t -= 9216; src = W_out; dst = tOut; K = 2048; N = 2048; kx = t & 63; ny = t >> 6; }
  __shared__ float T[32][36];
  const int k0 = kx * 32;
  const int n0 = ny * 32;
  const int r = threadIdx.x >> 3;
  const int c = (threadIdx.x & 7) * 4;
  *(float4*)&T[r][c] = *(const float4*)&src[(size_t)(k0 + r) * N + n0 + c];
  __syncthreads();
  bf16x4 o = {(__bf16)T[c + 0][r], (__bf16)T[c + 1][r],
              (__bf16)T[c + 2][r], (__bf16)T[c + 3][r]};
  *(bf16x4*)&dst[(size_t)(n0 + r) * K + k0 + c] = o;
}

// elementwise fp32 -> bf16 (n multiple of 1024)
__global__ __launch_bounds__(256) void cast_kernel(const float* __restrict__ src,
                                                   __bf16* __restrict__ dst) {
  const int i = blockIdx.x * 256 + threadIdx.x;
  float4 v = *(const float4*)&src[i * 4];
  bf16x4 o = {(__bf16)v.x, (__bf16)v.y, (__bf16)v.z, (__bf16)v.w};
  *(bf16x4*)&dst[i * 4] = o;
}

// cos/sin tables: (L, 128).  inv_freq[j] = 10000^(-j/64), j = d & 63.
__global__ void rope_table_kernel(float* __restrict__ cosT,
                                  float* __restrict__ sinT) {
  const int l = blockIdx.x;
  const int d = threadIdx.x;
  const int j = d & 63;
  const float inv = exp2f(-(float)j * 0.2076205059304601f);  // log2(1e4)/64
  const float ang = (float)l * inv;
  cosT[l * 128 + d] = cosf(ang);
  sinT[l * 128 + d] = sinf(ang);
}

// In-place RoPE on a (2048, W) row-major bf16 tensor; heads of 128 along W.
__global__ __launch_bounds__(256) void rope_bf16_kernel(__bf16* __restrict__ T,
                                                        const float* __restrict__ cosT,
                                                        const float* __restrict__ sinT,
                                                        int W) {
  __shared__ float row[4096];
  const int l = blockIdx.x;
  const int tid = threadIdx.x;
  __bf16* rp = T + (size_t)l * W;
  for (int e4 = tid; e4 * 4 < W; e4 += 256) {
    bf16x4 v = *(const bf16x4*)&rp[e4 * 4];
#pragma unroll
    for (int i = 0; i < 4; ++i) row[e4 * 4 + i] = (float)v[i];
  }
  __syncthreads();
  for (int e = tid; e < W; e += 256) {
    const int d = e & 127;
    const float c = cosT[l * 128 + d];
    const float s = sinT[l * 128 + d];
    const float t = row[e];
    const int base = e & ~127;
    const float rot = (d < 64) ? -row[base + d + 64] : row[base + d - 64];
    rp[e] = (__bf16)(t * c + rot * s);
  }
}

// (2048 l, 2048 dims) bf16  ->  (2048 dims, 2048 l) bf16
__global__ __launch_bounds__(256) void transpose_bf16_kernel(const __bf16* __restrict__ src,
                                                             __bf16* __restrict__ dst) {
  __shared__ __align__(16) __bf16 Ts[32][40];
  const int l0 = blockIdx.x * 32;
  const int d0 = blockIdx.y * 32;
  const int r = threadIdx.x >> 3;
  const int c = (threadIdx.x & 7) * 4;
  *(bf16x4*)&Ts[r][c] = *(const bf16x4*)&src[(size_t)(l0 + r) * 2048 + d0 + c];
  __syncthreads();
  bf16x4 o = {Ts[c + 0][r], Ts[c + 1][r], Ts[c + 2][r], Ts[c + 3][r]};
  *(bf16x4*)&dst[(size_t)(d0 + r) * 2048 + l0 + c] = o;
}

// W_lam (2048,16) f32 -> WlT (16,2048) bf16
__global__ __launch_bounds__(256) void lamT_kernel(const float* __restrict__ W_lam,
                                                   __bf16* __restrict__ WlT) {
  const int i = blockIdx.x * 256 + threadIdx.x;  // 0..32767
  const int k = i >> 4, n = i & 15;
  WlT[(size_t)n * 2048 + k] = (__bf16)W_lam[i];
}

// lam(l,h) = sigmoid(x_bf[l,:] . W_lam[:,h] + b_lam[h]) via MFMA (N=16).
__global__ __launch_bounds__(256) void lam_mfma_kernel(const __bf16* __restrict__ x_bf,
                                                       const __bf16* __restrict__ WlT,
                                                       const float* __restrict__ b_lam,
                                                       float* __restrict__ lam) {
  const int tid = threadIdx.x;
  const int w = tid >> 6, lane = tid & 63, quad = lane >> 4, l16 = lane & 15;
  const int m0 = (blockIdx.x * 4 + w) * 16;
  const __bf16* xrow = x_bf + (size_t)(m0 + l16) * 2048 + quad * 8;
  const __bf16* wrow = WlT + (size_t)l16 * 2048 + quad * 8;
  f32x4 acc[4];
#pragma unroll
  for (int u = 0; u < 4; ++u) acc[u] = (f32x4){0.f, 0.f, 0.f, 0.f};
  for (int k0 = 0; k0 < 2048; k0 += 128) {
#pragma unroll
    for (int u = 0; u < 4; ++u) {
      bf16x8 a = *(const bf16x8*)&xrow[k0 + u * 32];
      bf16x8 b = *(const bf16x8*)&wrow[k0 + u * 32];
      acc[u] = __builtin_amdgcn_mfma_f32_16x16x32_bf16(a, b, acc[u], 0, 0, 0);
    }
  }
  const float bl = b_lam[l16];
#pragma unroll
  for (int r = 0; r < 4; ++r) {
    const float v = acc[0][r] + acc[1][r] + acc[2][r] + acc[3][r] + bl;
    lam[(size_t)(m0 + quad * 4 + r) * 16 + l16] = 1.0f / (1.0f + __expf(-v));
  }
}

// ---------------------------------------------------------------------------
// MFMA flash attention: transposed-score softmax, 32 q-rows/wave, K-tile 64,
// DMA (global_load_lds) staging with XOR-swizzled LDS, fused Q-RoPE+scale.
//  Qb: (2048,4096) UN-roped bf16.  Kb: (2048,2048) roped bf16.
//  Vt: (2048 dims, 2048 l) bf16.   O: (32,2048,128) bf16.
//  Swizzle: Ks row r (16 chunks of 16B): stored chunk = c ^ (r&15).
//           Vs row d (8 chunks of 16B):  stored chunk = c ^ (d&7).
// ---------------------------------------------------------------------------
#define ATQ 128
__global__ __launch_bounds__(256, 2) void attn_mfma_kernel(const __bf16* __restrict__ Qb,
                                                           const __bf16* __restrict__ Kb,
                                                           const __bf16* __restrict__ Vt,
                                                           const float* __restrict__ cosT,
                                                           const float* __restrict__ sinT,
                                                           __bf16* __restrict__ O) {
  __shared__ __align__(16) __bf16 Ks[64 * 128];
  __shared__ __align__(16) __bf16 Vs[128 * 64];
  __shared__ __align__(16) __bf16 Ps[4][32][72];
  const int b = blockIdx.x;
  const int hv = b >> 8;                       // 0: heavy half, 1: light half
  const int ii = b & 255;
  const int h32 = ii >> 3;
  const int qt = hv ? (ii & 7) : 15 - (ii & 7);  // strict heavy-first
  const int q0 = qt * ATQ;
  const int tid = threadIdx.x;
  const int w = tid >> 6;
  const int lane = tid & 63;
  const int quad = lane >> 4;
  const int l16 = lane & 15;
  const int qoff = h32 * 128;
  const int kvoff = (h32 >> 1) * 128;
  const float qscale = 0.08838834764831845f;  // 1/sqrt(128), folded into Q
  const int qrow_base = q0 + w * 32;

  // ---- load Q, apply RoPE + scale in-register (lane holds d and d+-64) ----
  bf16x8 aq[2][4];
#pragma unroll
  for (int s = 0; s < 2; ++s) {
    const int l = qrow_base + s * 16 + l16;
    const size_t qbase = (size_t)l * 4096 + qoff + quad * 8;
    bf16x8 raw[4];
#pragma unroll
    for (int ks = 0; ks < 4; ++ks)
      raw[ks] = *(const bf16x8*)&Qb[qbase + ks * 32];
#pragma unroll
    for (int ks = 0; ks < 4; ++ks) {
      const float* cp = &cosT[l * 128 + ks * 32 + quad * 8];
      const float* sp = &sinT[l * 128 + ks * 32 + quad * 8];
      f32x4 c0 = *(const f32x4*)cp, c1 = *(const f32x4*)(cp + 4);
      f32x4 s0 = *(const f32x4*)sp, s1 = *(const f32x4*)(sp + 4);
#pragma unroll
      for (int j = 0; j < 8; ++j) {
        const float cv = (j < 4) ? c0[j & 3] : c1[j & 3];
        const float sv = (j < 4) ? s0[j & 3] : s1[j & 3];
        const float rot = (ks < 2) ? -(float)raw[ks + 2][j] : (float)raw[ks - 2][j];
        aq[s][ks][j] = (__bf16)(((float)raw[ks][j] * cv + rot * sv) * qscale);
      }
    }
  }

  f32x4 o[2][8];
#pragma unroll
  for (int s = 0; s < 2; ++s)
#pragma unroll
    for (int i = 0; i < 8; ++i) o[s][i] = (f32x4){0.f, 0.f, 0.f, 0.f};
  float m[2] = {-1e30f, -1e30f}, lsum[2] = {0.f, 0.f};

  const int ktmax = 2 * qt + 1;
  for (int kt = 0; kt <= ktmax; ++kt) {
    const int k0 = kt * 64;
    __syncthreads();  // prev iter's reads done before DMA overwrites
    // ---- DMA-stage K (64x128, swizzled) and V^T (128x64, swizzled) ----
#pragma unroll
    for (int d = 0; d < 4; ++d) {
      const int r0 = w * 16 + d * 4;             // 4 K-rows per DMA
      const int row = r0 + (lane >> 4);
      const int ck = (lane & 15) ^ (row & 15);
      const __bf16* ga = Kb + (size_t)(k0 + row) * 2048 + kvoff + ck * 8;
      __builtin_amdgcn_global_load_lds(
          (const __attribute__((address_space(1))) void*)ga,
          (__attribute__((address_space(3))) void*)&Ks[r0 * 128], 16, 0, 0);
      const int r0v = w * 32 + d * 8;            // 8 V-rows per DMA
      const int rowv = r0v + (lane >> 3);
      const int cv = (lane & 7) ^ (rowv & 7);
      const __bf16* gv = Vt + (size_t)(kvoff + rowv) * 2048 + k0 + cv * 8;
      __builtin_amdgcn_global_load_lds(
          (const __attribute__((address_space(1))) void*)gv,
          (__attribute__((address_space(3))) void*)&Vs[r0v * 64], 16, 0, 0);
    }
    __syncthreads();  // drains vmcnt (DMA) per barrier semantics
    // ---- S^T = K Q^T : 4 key m-tiles x 4 k-steps x 2 q-subtiles ----
    f32x4 st[2][4];
#pragma unroll
    for (int s = 0; s < 2; ++s)
#pragma unroll
      for (int t = 0; t < 4; ++t) st[s][t] = (f32x4){0.f, 0.f, 0.f, 0.f};
#pragma unroll
    for (int ks = 0; ks < 4; ++ks) {
#pragma unroll
      for (int t = 0; t < 4; ++t) {
        bf16x8 ak = *(bf16x8*)&Ks[(t * 16 + l16) * 128 + (((ks * 4 + quad) ^ l16) << 3)];
        st[0][t] = __builtin_amdgcn_mfma_f32_16x16x32_bf16(ak, aq[0][ks], st[0][t], 0, 0, 0);
        st[1][t] = __builtin_amdgcn_mfma_f32_16x16x32_bf16(ak, aq[1][ks], st[1][t], 0, 0, 0);
      }
    }
    // ---- online softmax (scale pre-folded into Q) ----
    const bool masked = (kt >= 2 * qt);
#pragma unroll
    for (int s = 0; s < 2; ++s) {
      const int q = qrow_base + s * 16 + l16;
      float rm = -1e30f;
      if (!masked) {
#pragma unroll
        for (int t = 0; t < 4; ++t)
#pragma unroll
          for (int r = 0; r < 4; ++r) rm = fmaxf(rm, st[s][t][r]);
      } else {
#pragma unroll
        for (int t = 0; t < 4; ++t)
#pragma unroll
          for (int r = 0; r < 4; ++r) {
            const int key = k0 + t * 16 + quad * 4 + r;
            if (key > q) st[s][t][r] = -1e30f;
            rm = fmaxf(rm, st[s][t][r]);
          }
      }
      rm = fmaxf(rm, __shfl_xor(rm, 16, 64));
      rm = fmaxf(rm, __shfl_xor(rm, 32, 64));
      const float mn = fmaxf(m[s], rm);
      const float alpha = __expf(m[s] - mn);
      float rs = 0.f;
#pragma unroll
      for (int t = 0; t < 4; ++t)
#pragma unroll
        for (int r = 0; r < 4; ++r) {
          st[s][t][r] = __expf(st[s][t][r] - mn);
          rs += st[s][t][r];
        }
      rs += __shfl_xor(rs, 16, 64);
      rs += __shfl_xor(rs, 32, 64);
      m[s] = mn;
      lsum[s] = lsum[s] * alpha + rs;
#pragma unroll
      for (int t = 0; t < 4; ++t) {
        bf16x4 pk = {(__bf16)st[s][t][0], (__bf16)st[s][t][1],
                     (__bf16)st[s][t][2], (__bf16)st[s][t][3]};
        *(bf16x4*)&Ps[w][s * 16 + l16][t * 16 + quad * 4] = pk;
      }
#pragma unroll
      for (int r = 0; r < 4; ++r) {
        const float ar = __shfl(alpha, quad * 4 + r, 64);
#pragma unroll
        for (int nt = 0; nt < 8; ++nt) o[s][nt][r] *= ar;
      }
    }
    // ---- O += P V : per-wave P (no barrier), each bv feeds 2 MFMAs ----
#pragma unroll
    for (int ks = 0; ks < 2; ++ks) {
      bf16x8 pa0 = *(bf16x8*)&Ps[w][l16][ks * 32 + quad * 8];
      bf16x8 pa1 = *(bf16x8*)&Ps[w][16 + l16][ks * 32 + quad * 8];
#pragma unroll
      for (int nt = 0; nt < 8; ++nt) {
        bf16x8 bv = *(bf16x8*)&Vs[(nt * 16 + l16) * 64 + (((ks * 4 + quad) ^ (l16 & 7)) << 3)];
        o[0][nt] = __builtin_amdgcn_mfma_f32_16x16x32_bf16(pa0, bv, o[0][nt], 0, 0, 0);
        o[1][nt] = __builtin_amdgcn_mfma_f32_16x16x32_bf16(pa1, bv, o[1][nt], 0, 0, 0);
      }
    }
  }
  // ---- epilogue: rows = s*16+quad*4+r, cols = nt*16+l16 ----
#pragma unroll
  for (int s = 0; s < 2; ++s) {
    const float linv = 1.0f / lsum[s];
#pragma unroll
    for (int r = 0; r < 4; ++r) {
      const float inv = __shfl(linv, quad * 4 + r, 64);
      const int row = qrow_base + s * 16 + quad * 4 + r;
      __bf16* dst = O + ((size_t)h32 * 2048 + row) * 128;
#pragma unroll
      for (int nt = 0; nt < 8; ++nt)
        dst[nt * 16 + l16] = (__bf16)(o[s][nt][r] * inv);
    }
  }
}

// y[l, h*128+d] = attn[2h, l, d] - lam[l,h] * attn[2h+1, l, d]   (bf16 in/out)
__global__ __launch_bounds__(256) void combine_kernel(const __bf16* __restrict__ attn,
                                                      const float* __restrict__ lam,
                                                      __bf16* __restrict__ y) {
  const int l = blockIdx.x;
  const int tid = threadIdx.x;
  const int h = tid >> 4;
  const int d = (tid & 15) * 8;
  const float lm = lam[l * 16 + h];
  bf16x8 a1 = *(const bf16x8*)&attn[((size_t)(2 * h) * 2048 + l) * 128 + d];
  bf16x8 a2 = *(const bf16x8*)&attn[((size_t)(2 * h + 1) * 2048 + l) * 128 + d];
  bf16x8 o;
#pragma unroll
  for (int i = 0; i < 8; ++i) o[i] = (__bf16)((float)a1[i] - lm * (float)a2[i]);
  *(bf16x8*)&y[(size_t)l * 2048 + h * 128 + d] = o;
}

extern "C" void kernel_launch(void* const* d_in, const int* in_sizes, int n_in,
                              void* d_out, int out_size, void* d_ws, size_t ws_size,
                              hipStream_t stream) {
  const float* x     = (const float*)d_in[0];
  const float* W_DKV = (const float*)d_in[1];
  const float* W_UK  = (const float*)d_in[2];
  const float* W_UV  = (const float*)d_in[3];
  const float* W_DQ  = (const float*)d_in[4];
  const float* W_UQ  = (const float*)d_in[5];
  const float* W_lam = (const float*)d_in[6];
  const float* b_lam = (const float*)d_in[7];
  const float* W_out = (const float*)d_in[8];
  float* out = (float*)d_out;

  char* ws = (char*)d_ws;
  #define MB(n) ((size_t)(n) << 20)
  __bf16* x_bf   = (__bf16*)(ws + MB(0));    //  8 MB (2048x2048)
  __bf16* Wt_DKV = (__bf16*)(ws + MB(8));    //  2 MB (512x2048)
  __bf16* Wt_DQ  = (__bf16*)(ws + MB(10));   //  4 MB (1024x2048)
  __bf16* c_kv   = (__bf16*)(ws + MB(14));   //  2 MB (2048x512)
  __bf16* c_q    = (__bf16*)(ws + MB(16));   //  4 MB (2048x1024)
  __bf16* Wt_UK  = (__bf16*)(ws + MB(20));   //  2 MB (2048x512)
  __bf16* Wt_UV  = (__bf16*)(ws + MB(22));   //  2 MB (2048x512)
  __bf16* Wt_UQ  = (__bf16*)(ws + MB(24));   //  8 MB (4096x1024)
  __bf16* k_bf   = (__bf16*)(ws + MB(32));   //  8 MB (2048x2048)
  __bf16* v_bf   = (__bf16*)(ws + MB(40));   //  8 MB (2048x2048)
  __bf16* y_bf   = (__bf16*)(ws + MB(40));   //  8 MB alias: v_bf dead after v_t
  __bf16* q_bf   = (__bf16*)(ws + MB(48));   // 16 MB (2048x4096) un-roped
  __bf16* v_t    = (__bf16*)(ws + MB(64));   //  8 MB (2048x2048)
  __bf16* attn   = (__bf16*)(ws + MB(72));   // 16 MB (32x2048x128) bf16
  float*  lam    = (float*)(ws + MB(88));    // 128 KB
  float*  cosT   = (float*)(ws + MB(89));    //  1 MB
  float*  sinT   = (float*)(ws + MB(90));    //  1 MB
  __bf16* WlT    = (__bf16*)(ws + MB(91));   // 64 KB (16x2048)
  __bf16* Wt_out = (__bf16*)(ws + MB(92));   //  8 MB (2048x2048)  (total 100 MB)

  rope_table_kernel<<<2048, 128, 0, stream>>>(cosT, sinT);
  cast_kernel<<<4096, 256, 0, stream>>>(x, x_bf);
  castT_all<<<13312, 256, 0, stream>>>(W_DKV, W_DQ, W_UK, W_UV, W_UQ, W_out,
                                       Wt_DKV, Wt_DQ, Wt_UK, Wt_UV, Wt_UQ, Wt_out);
  lamT_kernel<<<128, 256, 0, stream>>>(W_lam, WlT);
  // fused down-projections: DKV (4 x-tiles) + DQ (8 x-tiles)
  gemm_fused3<<<dim3(12, 16), 256, 0, stream>>>(
      x_bf, Wt_DKV, c_kv, 512, 2048, 4,
      x_bf, Wt_DQ,  c_q, 1024, 2048, 8,
      x_bf, Wt_DQ,  c_q, 1024, 2048);
  lam_mfma_kernel<<<32, 256, 0, stream>>>(x_bf, WlT, b_lam, lam);
  // fused up-projections: UK (16) + UV (16) + UQ (32)
  gemm_fused3<<<dim3(64, 16), 256, 0, stream>>>(
      c_kv, Wt_UK, k_bf, 2048, 512, 16,
      c_kv, Wt_UV, v_bf, 2048, 512, 16,
      c_q,  Wt_UQ, q_bf, 4096, 1024);
  rope_bf16_kernel<<<2048, 256, 0, stream>>>(k_bf, cosT, sinT, 2048);
  transpose_bf16_kernel<<<dim3(64, 64), 256, 0, stream>>>(v_bf, v_t);
  // flash attention (Q-rope fused inside; heavy halves launch first)
  attn_mfma_kernel<<<512, 256, 0, stream>>>(q_bf, k_bf, v_t, cosT, sinT, attn);
  combine_kernel<<<2048, 256, 0, stream>>>(attn, lam, y_bf);
  gemm_mfma<false><<<dim3(16, 16), 256, 0, stream>>>(y_bf, Wt_out, out, 2048, 2048, 2048);
}